// Round 2
// baseline (1796.326 us; speedup 1.0000x reference)
//
#include <hip/hip_runtime.h>
#include <hip/hip_bf16.h>

// ---------------- problem constants ----------------
#define NROWS 32768
#define DIM   512
#define D2    1024
#define KCODE 8192
#define DECAYF 0.99f
#define OMD    0.01f
#define MARGIN 0.0625f
#define CANDCAP 16

typedef __attribute__((ext_vector_type(4))) float f32x4;
typedef __attribute__((ext_vector_type(8))) short s16x8;
typedef __attribute__((ext_vector_type(8))) unsigned short u16x8;
typedef __attribute__((ext_vector_type(4))) unsigned short u16x4;

// ---------------- workspace layout (bytes) ----------------
#define WS_EMB16   0u            // K*1024 bf16 = 16,777,216 B
#define WS_YSQ     16777216u     // K f32      =     32,768 B
#define WS_NINT    16809984u     // K int      =     32,768 B
#define WS_ENT     16842752u     // 16 B
#define WS_CCOUNT  16842768u     // N int      =    131,072 B
#define WS_CAND    16973840u     // N*16 int   =  2,097,152 B
#define WS_FIDX    19070992u     // N int      =    131,072 B

// ---------------- output layout (f32 elements, return order) ----------------
#define OUT_ZQR  0
#define OUT_ZQI  16777216
#define OUT_LOSS 33554432
#define OUT_IDX  33587200
#define OUT_ENT  33619968
#define OUT_NEWW 33619969
#define OUT_NCS  42008577
#define OUT_NEMA 42016769

__device__ __forceinline__ unsigned short f2bf(float f) {
    unsigned u = __float_as_uint(f);
    u += 0x7FFFu + ((u >> 16) & 1u);   // round-to-nearest-even
    return (unsigned short)(u >> 16);
}

__device__ __forceinline__ float wredf(float v) {
    #pragma unroll
    for (int o = 32; o > 0; o >>= 1) v += __shfl_down(v, o, 64);
    return v;
}

__device__ __forceinline__ double wredd(double v) {
    #pragma unroll
    for (int o = 32; o > 0; o >>= 1) v += __shfl_down(v, o, 64);
    return __shfl(v, 0, 64);
}

// ULP of float32 at magnitude v (v normal, positive)
__device__ __forceinline__ double ulp32_of(double v) {
    return scalbn(1.0, ilogb(v) - 23);
}

// ============ 1) y_sq + emb -> bf16 ============
__global__ __launch_bounds__(256) void prep_emb(const float* __restrict__ emb,
                                                unsigned short* __restrict__ emb16,
                                                float* __restrict__ ysq) {
    int wave = threadIdx.x >> 6, lane = threadIdx.x & 63;
    int k = blockIdx.x * 4 + wave;
    const float4* src = (const float4*)(emb + (size_t)k * D2);
    u16x4* dst = (u16x4*)(emb16 + (size_t)k * D2);
    float s = 0.f;
    #pragma unroll
    for (int p = 0; p < 4; ++p) {
        float4 v = src[p * 64 + lane];
        s += v.x * v.x + v.y * v.y + v.z * v.z + v.w * v.w;
        u16x4 b; b[0] = f2bf(v.x); b[1] = f2bf(v.y); b[2] = f2bf(v.z); b[3] = f2bf(v.w);
        dst[p * 64 + lane] = b;
    }
    s = wredf(s);
    if (lane == 0) ysq[k] = s;
}

// ============ 2) bf16 MFMA approx-score + per-lane top4 + candidate merge ============
struct Pair { float v; int i; };

__global__ __launch_bounds__(256) void argmin_gemm(
    const float* __restrict__ zr, const float* __restrict__ zi,
    const unsigned short* __restrict__ emb16, const float* __restrict__ ysq,
    int* __restrict__ cand, int* __restrict__ ccount)
{
    __shared__ unsigned short bsh[2][16][1032];   // 16 codes x 1024 depth, +8 pad
    const int tid = threadIdx.x;
    const int wave = tid >> 6, lane = tid & 63;
    const int brow = lane & 15;          // code-in-chunk (B) / z tile-row (A)
    const int kb   = (lane >> 4) * 8;

    // ---- A fragments: 16 z-rows, full 1024 depth, in registers ----
    const int arow = blockIdx.x * 64 + wave * 16 + brow;
    s16x8 afrag[32];
    #pragma unroll
    for (int kt = 0; kt < 32; ++kt) {
        int k0 = kt * 32 + kb;
        const float* srcp = (k0 < 512) ? (zr + (size_t)arow * 512 + k0)
                                       : (zi + (size_t)arow * 512 + (k0 - 512));
        float4 v0 = *(const float4*)(srcp);
        float4 v1 = *(const float4*)(srcp + 4);
        s16x8 a;
        a[0] = (short)f2bf(v0.x); a[1] = (short)f2bf(v0.y);
        a[2] = (short)f2bf(v0.z); a[3] = (short)f2bf(v0.w);
        a[4] = (short)f2bf(v1.x); a[5] = (short)f2bf(v1.y);
        a[6] = (short)f2bf(v1.z); a[7] = (short)f2bf(v1.w);
        afrag[kt] = a;
    }

    float tv[4][4]; int ti[4][4];
    #pragma unroll
    for (int j = 0; j < 4; ++j)
        #pragma unroll
        for (int t = 0; t < 4; ++t) { tv[j][t] = 3.4e38f; ti[j][t] = 0; }

    const u16x8* esrc = (const u16x8*)emb16;
    u16x8 stg[8];
    // prologue: stage chunk 0
    #pragma unroll
    for (int p = 0; p < 8; ++p) stg[p] = esrc[p * 256 + tid];
    #pragma unroll
    for (int p = 0; p < 8; ++p) {
        int i8 = p * 256 + tid;
        *(u16x8*)&bsh[0][i8 >> 7][(i8 & 127) * 8] = stg[p];
    }
    __syncthreads();

    float ys_cur = ysq[brow];

    for (int c = 0; c < 512; ++c) {
        const int cur = c & 1;
        float ys_next = 0.f;
        if (c + 1 < 512) {
            ys_next = ysq[(c + 1) * 16 + brow];
            const u16x8* s2 = esrc + (size_t)(c + 1) * 2048;
            #pragma unroll
            for (int p = 0; p < 8; ++p) stg[p] = s2[p * 256 + tid];
        }
        f32x4 acc = {0.f, 0.f, 0.f, 0.f};
        #pragma unroll
        for (int kt = 0; kt < 32; ++kt) {
            s16x8 b = *(const s16x8*)&bsh[cur][brow][kt * 32 + kb];
            acc = __builtin_amdgcn_mfma_f32_16x16x32_bf16(afrag[kt], b, acc, 0, 0, 0);
        }
        const int code = c * 16 + brow;
        #pragma unroll
        for (int j = 0; j < 4; ++j) {
            float sc = fmaf(-2.f, acc[j], ys_cur);
            if (sc < tv[j][3]) {
                tv[j][3] = sc; ti[j][3] = code;
                if (tv[j][3] < tv[j][2]) { float fv = tv[j][3]; tv[j][3] = tv[j][2]; tv[j][2] = fv;
                                           int   fi = ti[j][3]; ti[j][3] = ti[j][2]; ti[j][2] = fi; }
                if (tv[j][2] < tv[j][1]) { float fv = tv[j][2]; tv[j][2] = tv[j][1]; tv[j][1] = fv;
                                           int   fi = ti[j][2]; ti[j][2] = ti[j][1]; ti[j][1] = fi; }
                if (tv[j][1] < tv[j][0]) { float fv = tv[j][1]; tv[j][1] = tv[j][0]; tv[j][0] = fv;
                                           int   fi = ti[j][1]; ti[j][1] = ti[j][0]; ti[j][0] = fi; }
            }
        }
        ys_cur = ys_next;
        if (c + 1 < 512) {
            const int nxt = cur ^ 1;
            #pragma unroll
            for (int p = 0; p < 8; ++p) {
                int i8 = p * 256 + tid;
                *(u16x8*)&bsh[nxt][i8 >> 7][(i8 & 127) * 8] = stg[p];
            }
        }
        __syncthreads();
    }

    // ---- merge per-lane top4 -> per-row candidate list ----
    Pair* mg = (Pair*)&bsh[0][0][0];   // 4*16*16*4*8B = 32KB
    const int rowbase = (lane >> 4) * 4;
    #pragma unroll
    for (int j = 0; j < 4; ++j) {
        int rr = rowbase + j;
        #pragma unroll
        for (int t = 0; t < 4; ++t) {
            Pair pp; pp.v = tv[j][t]; pp.i = ti[j][t];
            mg[(((wave * 16 + rr) * 16 + brow) * 4) + t] = pp;
        }
    }
    __syncthreads();
    if (tid < 64) {
        int w = tid >> 4, r = tid & 15;
        Pair* base = mg + (size_t)((w * 16 + r) * 16) * 4;  // 64 pairs
        float best = 3.4e38f;
        for (int i = 0; i < 64; ++i) best = fminf(best, base[i].v);
        float lim = best + MARGIN;
        int cnt = 0; int buf[CANDCAP];
        for (int i = 0; i < 64; ++i) {
            if (base[i].v < lim && cnt < CANDCAP) buf[cnt++] = base[i].i;
        }
        int grow = blockIdx.x * 64 + w * 16 + r;
        ccount[grow] = cnt;
        for (int i = 0; i < cnt; ++i) cand[grow * CANDCAP + i] = buf[i];
    }
}

// ============ 3) rescore mimicking numpy's f32 pipeline ============
// np computes d = fl32( fl32(x_sq + y_sq) - 2*fl32(dot) ), argmin lowest-index-first.
// x_sq lies ON the f32 grid of its own binade, so in the comparison it cancels:
//   d_k = x + G_uS(y_k) - G_ud(2*t_k),  G_u(v) = rint(v/u)*u
// where uS = ULP32(x_sq), ud = ULP32(d). Compare D_k = G_uS(y_k) - G_ud(2 t_k),
// exact ties -> lower index (numpy argmin first-occurrence rule).
__global__ __launch_bounds__(256) void cleanup(
    const float* __restrict__ zr, const float* __restrict__ zi,
    const float* __restrict__ emb, const int* __restrict__ cand,
    const int* __restrict__ ccount, int* __restrict__ fidx, float* __restrict__ out)
{
    int wave = threadIdx.x >> 6, lane = threadIdx.x & 63;
    int r = blockIdx.x * 4 + wave;
    int cnt = ccount[r];
    int best = cand[r * CANDCAP];
    if (cnt > 1) {
        // x_sq in f64 (only its binade is needed) + cache z in regs
        float zreg[16];
        double xs = 0.0;
        #pragma unroll
        for (int p = 0; p < 4; ++p) {
            int d4 = p * 64 + lane;
            const float4* zp = (d4 < 128) ? (const float4*)(zr + (size_t)r * 512)
                                          : ((const float4*)(zi + (size_t)r * 512) - 128);
            float4 zv = zp[d4];
            zreg[p * 4 + 0] = zv.x; zreg[p * 4 + 1] = zv.y;
            zreg[p * 4 + 2] = zv.z; zreg[p * 4 + 3] = zv.w;
            xs += (double)zv.x * zv.x + (double)zv.y * zv.y
                + (double)zv.z * zv.z + (double)zv.w * zv.w;
        }
        xs = wredd(xs);
        double uS = ulp32_of(xs);

        double bD = 1e300; int bi = 1 << 30;
        for (int i = 0; i < cnt; ++i) {
            int cdx = cand[r * CANDCAP + i];
            const float4* ep = (const float4*)(emb + (size_t)cdx * 1024);
            double ys = 0.0, tt = 0.0;
            #pragma unroll
            for (int p = 0; p < 4; ++p) {
                float4 ev = ep[p * 64 + lane];
                // np squares in f32 first, then sums
                float p0 = ev.x * ev.x, p1 = ev.y * ev.y, p2 = ev.z * ev.z, p3 = ev.w * ev.w;
                ys += (double)p0 + (double)p1 + (double)p2 + (double)p3;
                tt += (double)zreg[p * 4 + 0] * (double)ev.x
                    + (double)zreg[p * 4 + 1] * (double)ev.y
                    + (double)zreg[p * 4 + 2] * (double)ev.z
                    + (double)zreg[p * 4 + 3] * (double)ev.w;
            }
            ys = wredd(ys);
            tt = wredd(tt);
            float y32 = (float)ys;        // ~ np's f32 y_sq
            float t32 = (float)tt;        // ~ np's f32 materialized dot
            double dex = xs + ys - 2.0 * tt;
            double ud = ulp32_of(dex);
            double D = rint((double)y32 / uS) * uS - rint(2.0 * (double)t32 / ud) * ud;
            if (D < bD || (D == bD && cdx < bi)) { bD = D; bi = cdx; }
        }
        best = bi;
    }
    if (lane == 0) { fidx[r] = best; out[OUT_IDX + r] = (float)best; }
}

// ============ 4) new_ema_w = 0.99*ema_w ============
__global__ void init_ema(const float* __restrict__ emaw, float* __restrict__ out) {
    int i = blockIdx.x * blockDim.x + threadIdx.x;
    int stride = gridDim.x * blockDim.x;
    for (; i < KCODE * D2; i += stride) out[OUT_NEMA + i] = DECAYF * emaw[i];
}

// ============ 5) scatter counts + 0.01*z into new_ema_w ============
__global__ __launch_bounds__(256) void scatter(
    const float* __restrict__ zr, const float* __restrict__ zi,
    const int* __restrict__ fidx, int* __restrict__ nint, float* __restrict__ out)
{
    int wave = threadIdx.x >> 6, lane = threadIdx.x & 63;
    int r = blockIdx.x * 4 + wave;
    int idx = fidx[r];
    if (lane == 0) atomicAdd(nint + idx, 1);
    float* dst = out + OUT_NEMA + (size_t)idx * 1024;
    #pragma unroll
    for (int p = 0; p < 4; ++p) {
        int d4 = p * 64 + lane;
        const float4* zp = (d4 < 128) ? (const float4*)(zr + (size_t)r * 512)
                                      : ((const float4*)(zi + (size_t)r * 512) - 128);
        float4 zv = zp[d4];
        atomicAdd(dst + d4 * 4 + 0, OMD * zv.x);
        atomicAdd(dst + d4 * 4 + 1, OMD * zv.y);
        atomicAdd(dst + d4 * 4 + 2, OMD * zv.z);
        atomicAdd(dst + d4 * 4 + 3, OMD * zv.w);
    }
}

// ============ 6) new_w = clip(new_ema_w / cs) ============
__global__ void finalize_w(const float* __restrict__ emacs, const int* __restrict__ nint,
                           float* __restrict__ out) {
    int i = blockIdx.x * blockDim.x + threadIdx.x;
    int stride = gridDim.x * blockDim.x;
    for (; i < KCODE * D2; i += stride) {
        int k = i >> 10;
        float ncs = DECAYF * emacs[k] + OMD * (float)nint[k];
        float cs = ncs + 1e-5f;
        if (cs < 1.f) cs += 1.f;
        float w = out[OUT_NEMA + i] / cs;
        w = fminf(fmaxf(w, -5.f), 5.f);
        out[OUT_NEWW + i] = w;
    }
}

// ============ 7) new_cluster_size + entropy partial ============
__global__ __launch_bounds__(256) void cluster_fin(const float* __restrict__ emacs,
                                                   const int* __restrict__ nint,
                                                   float* __restrict__ out,
                                                   float* __restrict__ entacc) {
    int k = blockIdx.x * 256 + threadIdx.x;
    float n = (float)nint[k];
    float ncs = DECAYF * emacs[k] + OMD * n;
    out[OUT_NCS + k] = ncs;
    float p = n / 32768.f;
    float term = -p * logf(p + 1e-10f);
    __shared__ float red[256];
    red[threadIdx.x] = term;
    __syncthreads();
    for (int s = 128; s > 0; s >>= 1) {
        if (threadIdx.x < s) red[threadIdx.x] += red[threadIdx.x + s];
        __syncthreads();
    }
    if (threadIdx.x == 0) atomicAdd(entacc, red[0]);
}

__global__ void ent_fin(const float* __restrict__ entacc, float* __restrict__ out) {
    if (threadIdx.x == 0) out[OUT_ENT] = entacc[0] / logf(8192.f);
}

// ============ 8) z_q gather + loss ============
__global__ __launch_bounds__(256) void zq_loss(
    const float* __restrict__ zr, const float* __restrict__ zi,
    const float* __restrict__ emb, const int* __restrict__ fidx, float* __restrict__ out)
{
    int wave = threadIdx.x >> 6, lane = threadIdx.x & 63;
    int r = blockIdx.x * 4 + wave;
    int idx = fidx[r];
    const float4* ep = (const float4*)(emb + (size_t)idx * 1024);
    float acc = 0.f;
    #pragma unroll
    for (int p = 0; p < 4; ++p) {
        int d4 = p * 64 + lane;
        const float4* zp = (d4 < 128) ? (const float4*)(zr + (size_t)r * 512)
                                      : ((const float4*)(zi + (size_t)r * 512) - 128);
        float4 zv = zp[d4];
        float4 ev = ep[d4];
        float dx = ev.x - zv.x; acc += dx * dx;
        float dy = ev.y - zv.y; acc += dy * dy;
        float dz = ev.z - zv.z; acc += dz * dz;
        float dw = ev.w - zv.w; acc += dw * dw;
        float4* op = (d4 < 128) ? (float4*)(out + OUT_ZQR + (size_t)r * 512)
                                : ((float4*)(out + OUT_ZQI + (size_t)r * 512) - 128);
        op[d4] = ev;
    }
    acc = wredf(acc);
    if (lane == 0) out[OUT_LOSS + r] = 0.25f * acc * (1.f / 1024.f);
}

// ============ launcher ============
extern "C" void kernel_launch(void* const* d_in, const int* in_sizes, int n_in,
                              void* d_out, int out_size, void* d_ws, size_t ws_size,
                              hipStream_t stream)
{
    const float* zr    = (const float*)d_in[0];
    const float* zi    = (const float*)d_in[1];
    const float* emb   = (const float*)d_in[2];
    const float* emacs = (const float*)d_in[3];
    const float* emaw  = (const float*)d_in[4];
    float* out = (float*)d_out;
    char* ws = (char*)d_ws;

    unsigned short* emb16 = (unsigned short*)(ws + WS_EMB16);
    float* ysq    = (float*)(ws + WS_YSQ);
    int*   nint   = (int*)(ws + WS_NINT);
    float* entacc = (float*)(ws + WS_ENT);
    int*   ccount = (int*)(ws + WS_CCOUNT);
    int*   cand   = (int*)(ws + WS_CAND);
    int*   fidx   = (int*)(ws + WS_FIDX);

    hipMemsetAsync(ws + WS_NINT, 0, WS_CAND - WS_NINT, stream);  // nint + ent + ccount

    prep_emb   <<<2048, 256, 0, stream>>>(emb, emb16, ysq);
    argmin_gemm<<<512,  256, 0, stream>>>(zr, zi, emb16, ysq, cand, ccount);
    cleanup    <<<8192, 256, 0, stream>>>(zr, zi, emb, cand, ccount, fidx, out);
    init_ema   <<<2048, 256, 0, stream>>>(emaw, out);
    scatter    <<<8192, 256, 0, stream>>>(zr, zi, fidx, nint, out);
    finalize_w <<<2048, 256, 0, stream>>>(emacs, nint, out);
    cluster_fin<<<32,   256, 0, stream>>>(emacs, nint, out, entacc);
    ent_fin    <<<1,    64,  0, stream>>>(entacc, out);
    zq_loss    <<<8192, 256, 0, stream>>>(zr, zi, emb, fidx, out);
}

// Round 3
// 1535.598 us; speedup vs baseline: 1.1698x; 1.1698x over previous
//
#include <hip/hip_runtime.h>
#include <hip/hip_bf16.h>

// ---------------- problem constants ----------------
#define NROWS 32768
#define DIM   512
#define D2    1024
#define KCODE 8192
#define DECAYF 0.99f
#define OMD    0.01f
#define MARGIN 0.0625f
#define CANDCAP 16

typedef __attribute__((ext_vector_type(4))) float f32x4;
typedef __attribute__((ext_vector_type(16))) float f32x16;
typedef __attribute__((ext_vector_type(8))) short s16x8;
typedef __attribute__((ext_vector_type(4))) unsigned short u16x4;

// ---------------- workspace layout (bytes) ----------------
#define WS_EMB16   0u            // K*1024 bf16 = 16,777,216 B
#define WS_YSQ     16777216u     // K f32      =     32,768 B
#define WS_NINT    16809984u     // K int      =     32,768 B
#define WS_ENT     16842752u     // 16 B
#define WS_CCOUNT  16842768u     // N int      =    131,072 B
#define WS_CAND    16973840u     // N*16 int   =  2,097,152 B
#define WS_FIDX    19070992u     // N int      =    131,072 B

// ---------------- output layout (f32 elements, return order) ----------------
#define OUT_ZQR  0
#define OUT_ZQI  16777216
#define OUT_LOSS 33554432
#define OUT_IDX  33587200
#define OUT_ENT  33619968
#define OUT_NEWW 33619969
#define OUT_NCS  42008577
#define OUT_NEMA 42016769
// pair scratch lives inside OUT_NEWW region (dead until finalize_w), 8B-aligned:
#define PAIRS_OFF (OUT_NEWW + 1)   // 33619970*4 % 8 == 0; needs 25.2MB of 33.5MB

__device__ __forceinline__ unsigned short f2bf(float f) {
    unsigned u = __float_as_uint(f);
    u += 0x7FFFu + ((u >> 16) & 1u);   // round-to-nearest-even
    return (unsigned short)(u >> 16);
}

__device__ __forceinline__ float wredf(float v) {
    #pragma unroll
    for (int o = 32; o > 0; o >>= 1) v += __shfl_down(v, o, 64);
    return v;
}

__device__ __forceinline__ double wredd(double v) {
    #pragma unroll
    for (int o = 32; o > 0; o >>= 1) v += __shfl_down(v, o, 64);
    return __shfl(v, 0, 64);
}

// ULP of float32 at magnitude v (v normal, positive)
__device__ __forceinline__ double ulp32_of(double v) {
    return scalbn(1.0, ilogb(v) - 23);
}

// async global->LDS, 16B per lane; LDS dest = wave-uniform base + lane*16
__device__ __forceinline__ void gload_lds16(const void* g, void* l) {
    __builtin_amdgcn_global_load_lds(
        (const __attribute__((address_space(1))) unsigned int*)(g),
        (__attribute__((address_space(3))) unsigned int*)(l), 16, 0, 0);
}

// ============ 1) y_sq + emb -> bf16 ============
__global__ __launch_bounds__(256) void prep_emb(const float* __restrict__ emb,
                                                unsigned short* __restrict__ emb16,
                                                float* __restrict__ ysq) {
    int wave = threadIdx.x >> 6, lane = threadIdx.x & 63;
    int k = blockIdx.x * 4 + wave;
    const float4* src = (const float4*)(emb + (size_t)k * D2);
    u16x4* dst = (u16x4*)(emb16 + (size_t)k * D2);
    float s = 0.f;
    #pragma unroll
    for (int p = 0; p < 4; ++p) {
        float4 v = src[p * 64 + lane];
        s += v.x * v.x + v.y * v.y + v.z * v.z + v.w * v.w;
        u16x4 b; b[0] = f2bf(v.x); b[1] = f2bf(v.y); b[2] = f2bf(v.z); b[3] = f2bf(v.w);
        dst[p * 64 + lane] = b;
    }
    s = wredf(s);
    if (lane == 0) ysq[k] = s;
}

// ============ 2) 32x32x16 MFMA approx-score, A(32 rows/wave) in regs ============
// Block: 256 thr = 4 waves, 128 rows. Streams all 8192 codes in 32-code chunks,
// each chunk staged in two 512-depth halves (2 x 32KB LDS double buffer).
// LDS B-tile XOR-swizzled (chunk16B ^ (code&7)) via pre-swizzled global source.
// Per-lane-per-row top-3 (value + packed chunk ids) -> global pair buffer.
__global__ __launch_bounds__(256) void argmin_gemm(
    const float* __restrict__ zr, const float* __restrict__ zi,
    const unsigned short* __restrict__ emb16, const float* __restrict__ ysq,
    long long* __restrict__ pairs)
{
    __shared__ unsigned short bufs[2][16384];   // 2 x 32KB halves
    const int tid  = threadIdx.x;
    const int wave = tid >> 6, lane = tid & 63;
    const int colc = lane & 31;      // MFMA row (A) / col (B) index
    const int hh   = lane >> 5;      // k-subgroup

    // ---- A fragments: 32 rows per wave, full K=1024, in registers (256 VGPR) ----
    const int arow = blockIdx.x * 128 + wave * 32 + colc;
    const float* zrp = zr + (size_t)arow * 512 + hh * 8;
    const float* zip = zi + (size_t)arow * 512 + hh * 8;
    s16x8 afrag[64];
    #pragma unroll
    for (int kt = 0; kt < 32; ++kt) {
        float4 v0 = *(const float4*)(zrp + kt * 16);
        float4 v1 = *(const float4*)(zrp + kt * 16 + 4);
        s16x8 a;
        a[0] = (short)f2bf(v0.x); a[1] = (short)f2bf(v0.y);
        a[2] = (short)f2bf(v0.z); a[3] = (short)f2bf(v0.w);
        a[4] = (short)f2bf(v1.x); a[5] = (short)f2bf(v1.y);
        a[6] = (short)f2bf(v1.z); a[7] = (short)f2bf(v1.w);
        afrag[kt] = a;
    }
    #pragma unroll
    for (int kt = 0; kt < 32; ++kt) {
        float4 v0 = *(const float4*)(zip + kt * 16);
        float4 v1 = *(const float4*)(zip + kt * 16 + 4);
        s16x8 a;
        a[0] = (short)f2bf(v0.x); a[1] = (short)f2bf(v0.y);
        a[2] = (short)f2bf(v0.z); a[3] = (short)f2bf(v0.w);
        a[4] = (short)f2bf(v1.x); a[5] = (short)f2bf(v1.y);
        a[6] = (short)f2bf(v1.z); a[7] = (short)f2bf(v1.w);
        afrag[32 + kt] = a;
    }

    // per-lane per-row top-3 (sorted v0<=v1<=v2), chunk ids packed 3x8b
    float tv0[16], tv1[16], tv2[16];
    int cpk[16];
    #pragma unroll
    for (int g = 0; g < 16; ++g) { tv0[g] = 3.4e38f; tv1[g] = 3.4e38f; tv2[g] = 3.4e38f; cpk[g] = 0; }

    // stage half (chunk_, h_): 32 codes x 512 depth = 32KB, swizzled source
#define STAGE(dstbuf, chunk_, h_) do {                                          \
        const unsigned short* gb = emb16 + ((size_t)(chunk_) * 32 * 1024 + (size_t)(h_) * 512); \
        _Pragma("unroll")                                                       \
        for (int p = 0; p < 8; ++p) {                                           \
            int s_ = p * 256 + wave * 64 + lane;                                \
            int rw_ = s_ >> 6;                                                  \
            int cc_ = (s_ & 63) ^ (rw_ & 7);                                    \
            gload_lds16(gb + (size_t)rw_ * 1024 + cc_ * 8,                      \
                        &(dstbuf)[(p * 256 + wave * 64) * 8]);                  \
        }                                                                       \
    } while (0)

    const char* bb0 = (const char*)&bufs[0][0] + colc * 1024;
    const char* bb1 = (const char*)&bufs[1][0] + colc * 1024;
    const unsigned bxor = (unsigned)(colc & 7);

    STAGE(bufs[0], 0, 0);
    __syncthreads();

    for (int chunk = 0; chunk < 256; ++chunk) {
        // ---- half 0: compute bufs[0] (depth 0..511), stage bufs[1] ----
        STAGE(bufs[1], chunk, 1);
        f32x16 acc;
        #pragma unroll
        for (int g = 0; g < 16; ++g) acc[g] = 0.f;
        #pragma unroll
        for (int kt2 = 0; kt2 < 32; ++kt2) {
            s16x8 b = *(const s16x8*)(bb0 + ((((kt2 * 2) | hh) ^ bxor) << 4));
            acc = __builtin_amdgcn_mfma_f32_32x32x16_bf16(afrag[kt2], b, acc, 0, 0, 0);
        }
        __syncthreads();

        // ---- half 1: compute bufs[1] (depth 512..1023), stage next chunk ----
        if (chunk + 1 < 256) STAGE(bufs[0], chunk + 1, 0);
        #pragma unroll
        for (int kt2 = 0; kt2 < 32; ++kt2) {
            s16x8 b = *(const s16x8*)(bb1 + ((((kt2 * 2) | hh) ^ bxor) << 4));
            acc = __builtin_amdgcn_mfma_f32_32x32x16_bf16(afrag[32 + kt2], b, acc, 0, 0, 0);
        }
        float ysv = ysq[chunk * 32 + colc];
        #pragma unroll
        for (int g = 0; g < 16; ++g) {
            float sc = fmaf(-2.f, acc[g], ysv);
            if (sc < tv2[g]) {
                bool b1 = sc < tv1[g];
                bool b0 = sc < tv0[g];
                int cp = cpk[g];
                int ncp = b0 ? (((cp << 8) | chunk) & 0xFFFFFF)
                        : (b1 ? ((cp & 0xFF) | (chunk << 8) | ((cp & 0xFF00) << 8))
                              : ((cp & 0xFFFF) | (chunk << 16)));
                cpk[g] = ncp;
                float ov1 = tv1[g], ov0 = tv0[g];
                tv2[g] = b1 ? ov1 : sc;
                tv1[g] = b0 ? ov0 : (b1 ? sc : ov1);
                tv0[g] = b0 ? sc : ov0;
            }
        }
        __syncthreads();
    }
#undef STAGE

    // ---- write per-lane top-3 to global pair buffer: pairs[row][col*3 + t] ----
    #pragma unroll
    for (int g = 0; g < 16; ++g) {
        int rloc = (g & 3) + 8 * (g >> 2) + 4 * hh;           // C/D row mapping (m74/m101)
        int rowg = blockIdx.x * 128 + wave * 32 + rloc;
        size_t base = (size_t)rowg * 96 + colc * 3;
        int cp = cpk[g];
        pairs[base + 0] = ((long long)(unsigned)((cp        & 0xFF) * 32 + colc) << 32)
                        | (unsigned)__float_as_uint(tv0[g]);
        pairs[base + 1] = ((long long)(unsigned)(((cp >> 8) & 0xFF) * 32 + colc) << 32)
                        | (unsigned)__float_as_uint(tv1[g]);
        pairs[base + 2] = ((long long)(unsigned)(((cp >> 16) & 0xFF) * 32 + colc) << 32)
                        | (unsigned)__float_as_uint(tv2[g]);
    }
}

// ============ 2b) per-row merge of 96 pair slots -> candidate list ============
__global__ __launch_bounds__(256) void merge_rows(const long long* __restrict__ pairs,
                                                  int* __restrict__ cand,
                                                  int* __restrict__ ccount)
{
    int wave = threadIdx.x >> 6, lane = threadIdx.x & 63;
    int row = blockIdx.x * 4 + wave;
    const long long* pr = pairs + (size_t)row * 96;
    long long p0 = pr[lane];
    float v0v = __uint_as_float((unsigned)p0);
    int   i0  = (int)(p0 >> 32);
    float v1v = 3.4e38f; int i1 = 0;
    if (lane < 32) {
        long long p1 = pr[64 + lane];
        v1v = __uint_as_float((unsigned)p1);
        i1  = (int)(p1 >> 32);
    }
    float m = fminf(v0v, v1v);
    #pragma unroll
    for (int o = 32; o > 0; o >>= 1) m = fminf(m, __shfl_xor(m, o, 64));
    float lim = m + MARGIN;
    unsigned long long m0 = __ballot(v0v < lim);
    unsigned long long m1 = __ballot(v1v < lim);
    int t0 = __popcll(m0);
    int cnt = t0 + __popcll(m1);
    if (cnt > CANDCAP) cnt = CANDCAP;
    unsigned long long below = (lane == 63) ? 0xFFFFFFFFFFFFFFFFull >> 1
                                            : ((1ull << lane) - 1);
    if (v0v < lim) {
        int pos = __popcll(m0 & below);
        if (pos < CANDCAP) cand[(size_t)row * CANDCAP + pos] = i0;
    }
    if (v1v < lim) {
        int pos = t0 + __popcll(m1 & below);
        if (pos < CANDCAP) cand[(size_t)row * CANDCAP + pos] = i1;
    }
    if (lane == 0) ccount[row] = cnt;
}

// ============ 3) rescore mimicking numpy's f32 pipeline ============
__global__ __launch_bounds__(256) void cleanup(
    const float* __restrict__ zr, const float* __restrict__ zi,
    const float* __restrict__ emb, const int* __restrict__ cand,
    const int* __restrict__ ccount, int* __restrict__ fidx, float* __restrict__ out)
{
    int wave = threadIdx.x >> 6, lane = threadIdx.x & 63;
    int r = blockIdx.x * 4 + wave;
    int cnt = ccount[r];
    int best = cand[r * CANDCAP];
    if (cnt > 1) {
        float zreg[16];
        double xs = 0.0;
        #pragma unroll
        for (int p = 0; p < 4; ++p) {
            int d4 = p * 64 + lane;
            const float4* zp = (d4 < 128) ? (const float4*)(zr + (size_t)r * 512)
                                          : ((const float4*)(zi + (size_t)r * 512) - 128);
            float4 zv = zp[d4];
            zreg[p * 4 + 0] = zv.x; zreg[p * 4 + 1] = zv.y;
            zreg[p * 4 + 2] = zv.z; zreg[p * 4 + 3] = zv.w;
            xs += (double)zv.x * zv.x + (double)zv.y * zv.y
                + (double)zv.z * zv.z + (double)zv.w * zv.w;
        }
        xs = wredd(xs);
        double uS = ulp32_of(xs);

        double bD = 1e300; int bi = 1 << 30;
        for (int i = 0; i < cnt; ++i) {
            int cdx = cand[r * CANDCAP + i];
            const float4* ep = (const float4*)(emb + (size_t)cdx * 1024);
            double ys = 0.0, tt = 0.0;
            #pragma unroll
            for (int p = 0; p < 4; ++p) {
                float4 ev = ep[p * 64 + lane];
                float p0 = ev.x * ev.x, p1 = ev.y * ev.y, p2 = ev.z * ev.z, p3 = ev.w * ev.w;
                ys += (double)p0 + (double)p1 + (double)p2 + (double)p3;
                tt += (double)zreg[p * 4 + 0] * (double)ev.x
                    + (double)zreg[p * 4 + 1] * (double)ev.y
                    + (double)zreg[p * 4 + 2] * (double)ev.z
                    + (double)zreg[p * 4 + 3] * (double)ev.w;
            }
            ys = wredd(ys);
            tt = wredd(tt);
            float y32 = (float)ys;
            float t32 = (float)tt;
            double dex = xs + ys - 2.0 * tt;
            double ud = ulp32_of(dex);
            double D = rint((double)y32 / uS) * uS - rint(2.0 * (double)t32 / ud) * ud;
            if (D < bD || (D == bD && cdx < bi)) { bD = D; bi = cdx; }
        }
        best = bi;
    }
    if (lane == 0) { fidx[r] = best; out[OUT_IDX + r] = (float)best; }
}

// ============ 4) new_ema_w = 0.99*ema_w ============
__global__ void init_ema(const float* __restrict__ emaw, float* __restrict__ out) {
    int i = blockIdx.x * blockDim.x + threadIdx.x;
    int stride = gridDim.x * blockDim.x;
    for (; i < KCODE * D2; i += stride) out[OUT_NEMA + i] = DECAYF * emaw[i];
}

// ============ 5) scatter counts + 0.01*z into new_ema_w ============
__global__ __launch_bounds__(256) void scatter(
    const float* __restrict__ zr, const float* __restrict__ zi,
    const int* __restrict__ fidx, int* __restrict__ nint, float* __restrict__ out)
{
    int wave = threadIdx.x >> 6, lane = threadIdx.x & 63;
    int r = blockIdx.x * 4 + wave;
    int idx = fidx[r];
    if (lane == 0) atomicAdd(nint + idx, 1);
    float* dst = out + OUT_NEMA + (size_t)idx * 1024;
    #pragma unroll
    for (int p = 0; p < 4; ++p) {
        int d4 = p * 64 + lane;
        const float4* zp = (d4 < 128) ? (const float4*)(zr + (size_t)r * 512)
                                      : ((const float4*)(zi + (size_t)r * 512) - 128);
        float4 zv = zp[d4];
        atomicAdd(dst + d4 * 4 + 0, OMD * zv.x);
        atomicAdd(dst + d4 * 4 + 1, OMD * zv.y);
        atomicAdd(dst + d4 * 4 + 2, OMD * zv.z);
        atomicAdd(dst + d4 * 4 + 3, OMD * zv.w);
    }
}

// ============ 6) new_w = clip(new_ema_w / cs) ============
__global__ void finalize_w(const float* __restrict__ emacs, const int* __restrict__ nint,
                           float* __restrict__ out) {
    int i = blockIdx.x * blockDim.x + threadIdx.x;
    int stride = gridDim.x * blockDim.x;
    for (; i < KCODE * D2; i += stride) {
        int k = i >> 10;
        float ncs = DECAYF * emacs[k] + OMD * (float)nint[k];
        float cs = ncs + 1e-5f;
        if (cs < 1.f) cs += 1.f;
        float w = out[OUT_NEMA + i] / cs;
        w = fminf(fmaxf(w, -5.f), 5.f);
        out[OUT_NEWW + i] = w;
    }
}

// ============ 7) new_cluster_size + entropy partial ============
__global__ __launch_bounds__(256) void cluster_fin(const float* __restrict__ emacs,
                                                   const int* __restrict__ nint,
                                                   float* __restrict__ out,
                                                   float* __restrict__ entacc) {
    int k = blockIdx.x * 256 + threadIdx.x;
    float n = (float)nint[k];
    float ncs = DECAYF * emacs[k] + OMD * n;
    out[OUT_NCS + k] = ncs;
    float p = n / 32768.f;
    float term = -p * logf(p + 1e-10f);
    __shared__ float red[256];
    red[threadIdx.x] = term;
    __syncthreads();
    for (int s = 128; s > 0; s >>= 1) {
        if (threadIdx.x < s) red[threadIdx.x] += red[threadIdx.x + s];
        __syncthreads();
    }
    if (threadIdx.x == 0) atomicAdd(entacc, red[0]);
}

__global__ void ent_fin(const float* __restrict__ entacc, float* __restrict__ out) {
    if (threadIdx.x == 0) out[OUT_ENT] = entacc[0] / logf(8192.f);
}

// ============ 8) z_q gather + loss ============
__global__ __launch_bounds__(256) void zq_loss(
    const float* __restrict__ zr, const float* __restrict__ zi,
    const float* __restrict__ emb, const int* __restrict__ fidx, float* __restrict__ out)
{
    int wave = threadIdx.x >> 6, lane = threadIdx.x & 63;
    int r = blockIdx.x * 4 + wave;
    int idx = fidx[r];
    const float4* ep = (const float4*)(emb + (size_t)idx * 1024);
    float acc = 0.f;
    #pragma unroll
    for (int p = 0; p < 4; ++p) {
        int d4 = p * 64 + lane;
        const float4* zp = (d4 < 128) ? (const float4*)(zr + (size_t)r * 512)
                                      : ((const float4*)(zi + (size_t)r * 512) - 128);
        float4 zv = zp[d4];
        float4 ev = ep[d4];
        float dx = ev.x - zv.x; acc += dx * dx;
        float dy = ev.y - zv.y; acc += dy * dy;
        float dz = ev.z - zv.z; acc += dz * dz;
        float dw = ev.w - zv.w; acc += dw * dw;
        float4* op = (d4 < 128) ? (float4*)(out + OUT_ZQR + (size_t)r * 512)
                                : ((float4*)(out + OUT_ZQI + (size_t)r * 512) - 128);
        op[d4] = ev;
    }
    acc = wredf(acc);
    if (lane == 0) out[OUT_LOSS + r] = 0.25f * acc * (1.f / 1024.f);
}

// ============ launcher ============
extern "C" void kernel_launch(void* const* d_in, const int* in_sizes, int n_in,
                              void* d_out, int out_size, void* d_ws, size_t ws_size,
                              hipStream_t stream)
{
    const float* zr    = (const float*)d_in[0];
    const float* zi    = (const float*)d_in[1];
    const float* emb   = (const float*)d_in[2];
    const float* emacs = (const float*)d_in[3];
    const float* emaw  = (const float*)d_in[4];
    float* out = (float*)d_out;
    char* ws = (char*)d_ws;

    unsigned short* emb16 = (unsigned short*)(ws + WS_EMB16);
    float* ysq    = (float*)(ws + WS_YSQ);
    int*   nint   = (int*)(ws + WS_NINT);
    float* entacc = (float*)(ws + WS_ENT);
    int*   ccount = (int*)(ws + WS_CCOUNT);
    int*   cand   = (int*)(ws + WS_CAND);
    int*   fidx   = (int*)(ws + WS_FIDX);
    long long* pairs = (long long*)(out + PAIRS_OFF);   // scratch inside new_w region

    hipMemsetAsync(ws + WS_NINT, 0, WS_CAND - WS_NINT, stream);  // nint + ent + ccount

    prep_emb   <<<2048, 256, 0, stream>>>(emb, emb16, ysq);
    argmin_gemm<<<256,  256, 0, stream>>>(zr, zi, emb16, ysq, pairs);
    merge_rows <<<8192, 256, 0, stream>>>(pairs, cand, ccount);
    cleanup    <<<8192, 256, 0, stream>>>(zr, zi, emb, cand, ccount, fidx, out);
    init_ema   <<<2048, 256, 0, stream>>>(emaw, out);
    scatter    <<<8192, 256, 0, stream>>>(zr, zi, fidx, nint, out);
    finalize_w <<<2048, 256, 0, stream>>>(emacs, nint, out);   // overwrites pairs region
    cluster_fin<<<32,   256, 0, stream>>>(emacs, nint, out, entacc);
    ent_fin    <<<1,    64,  0, stream>>>(entacc, out);
    zq_loss    <<<8192, 256, 0, stream>>>(zr, zi, emb, fidx, out);
}

// Round 4
// 953.091 us; speedup vs baseline: 1.8847x; 1.6112x over previous
//
#include <hip/hip_runtime.h>
#include <hip/hip_bf16.h>

// ---------------- problem constants ----------------
#define NROWS 32768
#define DIM   512
#define D2    1024
#define KCODE 8192
#define DECAYF 0.99f
#define OMD    0.01f
#define MARGIN 0.30f
#define CANDCAP 16
#define ZMAX 6.0f
#define IRANGE 0.04419417382415922f   // 1/sqrt(512)

typedef __attribute__((ext_vector_type(4))) float f32x4;
typedef __attribute__((ext_vector_type(4))) int   v4i;
typedef __attribute__((ext_vector_type(16))) int  i32x16;
typedef __attribute__((ext_vector_type(4))) unsigned short u16x4;

// ---------------- workspace layout (bytes) ----------------
#define WS_EMB8    0u            // K*1024 i8  =  8,388,608 B
#define WS_YSQ     8388608u      // K f32      =     32,768 B
#define WS_NINT    8421376u      // K int      =     32,768 B
#define WS_ENT     8454144u      // 16 B
#define WS_CCOUNT  8454160u      // N int      =    131,072 B
#define WS_CAND    8585232u      // N*16 int   =  2,097,152 B
#define WS_FIDX    10682384u     // N int      =    131,072 B

// ---------------- output layout (f32 elements, return order) ----------------
#define OUT_ZQR  0
#define OUT_ZQI  16777216
#define OUT_LOSS 33554432
#define OUT_IDX  33587200
#define OUT_ENT  33619968
#define OUT_NEWW 33619969
#define OUT_NCS  42008577
#define OUT_NEMA 42016769
// pairs scratch: 32768 rows x 128 slots x 8B = 33.5MB, lives in OUT_ZQR region
// (dead until zq_loss, which runs after merge_rows consumed pairs).

__device__ __forceinline__ float wredf(float v) {
    #pragma unroll
    for (int o = 32; o > 0; o >>= 1) v += __shfl_down(v, o, 64);
    return v;
}

__device__ __forceinline__ double wredd(double v) {
    #pragma unroll
    for (int o = 32; o > 0; o >>= 1) v += __shfl_down(v, o, 64);
    return __shfl(v, 0, 64);
}

// ULP of float32 at magnitude v (v normal, positive)
__device__ __forceinline__ double ulp32_of(double v) {
    return scalbn(1.0, ilogb(v) - 23);
}

// async global->LDS, 16B per lane; LDS dest = wave-uniform base + lane*16
__device__ __forceinline__ void gload_lds16(const void* g, void* l) {
    __builtin_amdgcn_global_load_lds(
        (const __attribute__((address_space(1))) unsigned int*)(g),
        (__attribute__((address_space(3))) unsigned int*)(l), 16, 0, 0);
}

// quantize 4 floats -> 4 packed i8 (byte0 = x)
__device__ __forceinline__ int q4(float4 v, float s) {
    int a = (int)rintf(fminf(fmaxf(v.x * s, -127.f), 127.f));
    int b = (int)rintf(fminf(fmaxf(v.y * s, -127.f), 127.f));
    int c = (int)rintf(fminf(fmaxf(v.z * s, -127.f), 127.f));
    int d = (int)rintf(fminf(fmaxf(v.w * s, -127.f), 127.f));
    return (a & 255) | ((b & 255) << 8) | ((c & 255) << 16) | ((d & 255) << 24);
}

// ============ 1) y_sq + emb -> i8 ============
__global__ __launch_bounds__(256) void prep_emb(const float* __restrict__ emb,
                                                char* __restrict__ emb8,
                                                float* __restrict__ ysq) {
    int wave = threadIdx.x >> 6, lane = threadIdx.x & 63;
    int k = blockIdx.x * 4 + wave;
    const float4* src = (const float4*)(emb + (size_t)k * D2);
    v4i* dst = (v4i*)(emb8 + (size_t)k * D2);
    const float es = 127.0f / IRANGE;
    float s = 0.f;
    float4 v0 = src[lane * 4 + 0];
    float4 v1 = src[lane * 4 + 1];
    float4 v2 = src[lane * 4 + 2];
    float4 v3 = src[lane * 4 + 3];
    s += v0.x*v0.x + v0.y*v0.y + v0.z*v0.z + v0.w*v0.w;
    s += v1.x*v1.x + v1.y*v1.y + v1.z*v1.z + v1.w*v1.w;
    s += v2.x*v2.x + v2.y*v2.y + v2.z*v2.z + v2.w*v2.w;
    s += v3.x*v3.x + v3.y*v3.y + v3.z*v3.z + v3.w*v3.w;
    v4i pk; pk[0] = q4(v0, es); pk[1] = q4(v1, es); pk[2] = q4(v2, es); pk[3] = q4(v3, es);
    dst[lane] = pk;
    s = wredf(s);
    if (lane == 0) ysq[k] = s;
}

// ============ 2) i8 MFMA approx-score, A(32 rows/wave, full K) in 128 regs ============
// Grid 512 = 256 row-blocks x 2 code-slices. Block: 4 waves, 128 rows, 4096 codes.
// Chunk = 32 codes; staged in two 512-depth halves (2 x 16KB LDS double buffer),
// XOR-swizzled (16B-chunk ^ (code&7)) via pre-swizzled global source.
// Per-lane-per-row top-2 -> global pair buffer (row x [slice*64 + col*2 + t]).
__global__ __launch_bounds__(256, 2) void argmin_gemm(
    const float* __restrict__ zr, const float* __restrict__ zi,
    const char* __restrict__ emb8, const float* __restrict__ ysq,
    long long* __restrict__ pairs)
{
    __shared__ char bufs[2][16384];   // 2 x 16KB halves
    const int tid  = threadIdx.x;
    const int wave = tid >> 6, lane = tid & 63;
    const int colc = lane & 31;      // A row / B col index
    const int hh   = lane >> 5;      // k-subgroup
    const int rowblk = blockIdx.x >> 1;
    const int slice  = blockIdx.x & 1;

    // ---- A fragments: 32 rows/wave, full K=1024, i8, 128 VGPR ----
    const int arow = rowblk * 128 + wave * 32 + colc;
    const float zs = 127.0f / ZMAX;
    const float* zrp = zr + (size_t)arow * 512 + hh * 16;
    const float* zip = zi + (size_t)arow * 512 + hh * 16;
    v4i afrag[32];
    #pragma unroll
    for (int ft = 0; ft < 16; ++ft) {
        const float4* p = (const float4*)(zrp + ft * 32);
        v4i a; a[0] = q4(p[0], zs); a[1] = q4(p[1], zs); a[2] = q4(p[2], zs); a[3] = q4(p[3], zs);
        afrag[ft] = a;
    }
    #pragma unroll
    for (int ft = 0; ft < 16; ++ft) {
        const float4* p = (const float4*)(zip + ft * 32);
        v4i a; a[0] = q4(p[0], zs); a[1] = q4(p[1], zs); a[2] = q4(p[2], zs); a[3] = q4(p[3], zs);
        afrag[16 + ft] = a;
    }

    // per-lane per-row top-2 (sorted v0<=v1), chunk ids packed 2x8b
    float tv0[16], tv1[16];
    int cpk[16];
    #pragma unroll
    for (int g = 0; g < 16; ++g) { tv0[g] = 3.4e38f; tv1[g] = 3.4e38f; cpk[g] = 0; }

    const char* gslice = emb8 + (size_t)slice * 4096 * 1024;
    const float* yslice = ysq + slice * 4096;

    // stage half (chunk_, h_): 32 codes x 512 depth i8 = 16KB, swizzled source
#define STAGE(dstbuf, chunk_, h_) do {                                           \
        const char* gb = gslice + ((size_t)(chunk_) * 32 * 1024 + (size_t)(h_) * 512); \
        _Pragma("unroll")                                                        \
        for (int p = 0; p < 4; ++p) {                                            \
            int s_ = p * 4096 + wave * 1024 + lane * 16;                         \
            int code_ = s_ >> 9;                                                 \
            int c16p_ = (s_ & 511) >> 4;                                         \
            gload_lds16(gb + (size_t)code_ * 1024 + ((c16p_ ^ (code_ & 7)) << 4), \
                        &(dstbuf)[p * 4096 + wave * 1024]);                      \
        }                                                                        \
    } while (0)

    const char* bb0 = &bufs[0][0] + colc * 512;
    const char* bb1 = &bufs[1][0] + colc * 512;
    const int bxor = colc & 7;
    const float sfac = 2.0f * (ZMAX / 127.0f) * (IRANGE / 127.0f);

    STAGE(bufs[0], 0, 0);
    __syncthreads();

    for (int c = 0; c < 128; ++c) {
        STAGE(bufs[1], c, 1);
        i32x16 acc0, acc1;
        #pragma unroll
        for (int g = 0; g < 16; ++g) { acc0[g] = 0; acc1[g] = 0; }
        #pragma unroll
        for (int kt = 0; kt < 16; kt += 2) {
            v4i b0 = *(const v4i*)(bb0 + ((((kt    ) * 2 + hh) ^ bxor) << 4));
            v4i b1 = *(const v4i*)(bb0 + ((((kt + 1) * 2 + hh) ^ bxor) << 4));
            acc0 = __builtin_amdgcn_mfma_i32_32x32x32_i8(afrag[kt],     b0, acc0, 0, 0, 0);
            acc1 = __builtin_amdgcn_mfma_i32_32x32x32_i8(afrag[kt + 1], b1, acc1, 0, 0, 0);
        }
        __syncthreads();

        if (c + 1 < 128) STAGE(bufs[0], c + 1, 0);
        #pragma unroll
        for (int kt = 0; kt < 16; kt += 2) {
            v4i b0 = *(const v4i*)(bb1 + ((((kt    ) * 2 + hh) ^ bxor) << 4));
            v4i b1 = *(const v4i*)(bb1 + ((((kt + 1) * 2 + hh) ^ bxor) << 4));
            acc0 = __builtin_amdgcn_mfma_i32_32x32x32_i8(afrag[16 + kt],     b0, acc0, 0, 0, 0);
            acc1 = __builtin_amdgcn_mfma_i32_32x32x32_i8(afrag[16 + kt + 1], b1, acc1, 0, 0, 0);
        }
        float ysv = yslice[c * 32 + colc];
        #pragma unroll
        for (int g = 0; g < 16; ++g) {
            float fdot = (float)(acc0[g] + acc1[g]);
            float sc = fmaf(-sfac, fdot, ysv);
            if (sc < tv1[g]) {
                bool b0 = sc < tv0[g];
                int cp = cpk[g];
                cpk[g] = b0 ? (((cp & 0xFF) << 8) | c) : ((cp & 0xFF) | (c << 8));
                float ov0 = tv0[g];
                tv1[g] = b0 ? ov0 : sc;
                tv0[g] = b0 ? sc : ov0;
            }
        }
        __syncthreads();
    }
#undef STAGE

    // ---- write per-lane top-2 to pair buffer: pairs[row][slice*64 + col*2 + t] ----
    #pragma unroll
    for (int g = 0; g < 16; ++g) {
        int rloc = (g & 3) + 8 * (g >> 2) + 4 * hh;       // C/D row mapping (m74/m101)
        int rowg = rowblk * 128 + wave * 32 + rloc;
        size_t base = (size_t)rowg * 128 + slice * 64 + colc * 2;
        int cp = cpk[g];
        int code0 = slice * 4096 + (cp & 0xFF) * 32 + colc;
        int code1 = slice * 4096 + ((cp >> 8) & 0xFF) * 32 + colc;
        pairs[base + 0] = ((long long)(unsigned)code0 << 32) | (unsigned)__float_as_uint(tv0[g]);
        pairs[base + 1] = ((long long)(unsigned)code1 << 32) | (unsigned)__float_as_uint(tv1[g]);
    }
}

// ============ 2b) per-row merge of 128 pair slots -> candidate list ============
__global__ __launch_bounds__(256) void merge_rows(const long long* __restrict__ pairs,
                                                  int* __restrict__ cand,
                                                  int* __restrict__ ccount)
{
    int wave = threadIdx.x >> 6, lane = threadIdx.x & 63;
    int row = blockIdx.x * 4 + wave;
    const long long* pr = pairs + (size_t)row * 128;
    long long p0 = pr[lane];
    long long p1 = pr[64 + lane];
    float v0v = __uint_as_float((unsigned)p0);
    int   i0  = (int)(p0 >> 32);
    float v1v = __uint_as_float((unsigned)p1);
    int   i1  = (int)(p1 >> 32);
    float m = fminf(v0v, v1v);
    #pragma unroll
    for (int o = 32; o > 0; o >>= 1) m = fminf(m, __shfl_xor(m, o, 64));
    float lim = m + MARGIN;
    unsigned long long m0 = __ballot(v0v < lim);
    unsigned long long m1 = __ballot(v1v < lim);
    int t0 = __popcll(m0);
    int cnt = t0 + __popcll(m1);
    if (cnt > CANDCAP) cnt = CANDCAP;
    unsigned long long below = (lane == 63) ? 0xFFFFFFFFFFFFFFFFull >> 1
                                            : ((1ull << lane) - 1);
    if (v0v < lim) {
        int pos = __popcll(m0 & below);
        if (pos < CANDCAP) cand[(size_t)row * CANDCAP + pos] = i0;
    }
    if (v1v < lim) {
        int pos = t0 + __popcll(m1 & below);
        if (pos < CANDCAP) cand[(size_t)row * CANDCAP + pos] = i1;
    }
    if (lane == 0) ccount[row] = cnt;
}

// ============ 3) rescore mimicking numpy's f32 pipeline ============
// np: d = fl32( fl32(x_sq + y_sq) - 2*fl32(dot) ), argmin lowest-index-first.
// x_sq lies ON the f32 grid of its own binade -> cancels; compare
// D_k = G_uS(y_k) - G_ud(2 t_k), grid G_u(v) = rint(v/u)*u, ties -> lower index.
__global__ __launch_bounds__(256) void cleanup(
    const float* __restrict__ zr, const float* __restrict__ zi,
    const float* __restrict__ emb, const int* __restrict__ cand,
    const int* __restrict__ ccount, int* __restrict__ fidx, float* __restrict__ out)
{
    int wave = threadIdx.x >> 6, lane = threadIdx.x & 63;
    int r = blockIdx.x * 4 + wave;
    int cnt = ccount[r];
    int best = cand[r * CANDCAP];
    if (cnt > 1) {
        float zreg[16];
        double xs = 0.0;
        #pragma unroll
        for (int p = 0; p < 4; ++p) {
            int d4 = p * 64 + lane;
            const float4* zp = (d4 < 128) ? (const float4*)(zr + (size_t)r * 512)
                                          : ((const float4*)(zi + (size_t)r * 512) - 128);
            float4 zv = zp[d4];
            zreg[p * 4 + 0] = zv.x; zreg[p * 4 + 1] = zv.y;
            zreg[p * 4 + 2] = zv.z; zreg[p * 4 + 3] = zv.w;
            xs += (double)zv.x * zv.x + (double)zv.y * zv.y
                + (double)zv.z * zv.z + (double)zv.w * zv.w;
        }
        xs = wredd(xs);
        double uS = ulp32_of(xs);

        double bD = 1e300; int bi = 1 << 30;
        for (int i = 0; i < cnt; ++i) {
            int cdx = cand[r * CANDCAP + i];
            const float4* ep = (const float4*)(emb + (size_t)cdx * 1024);
            double ys = 0.0, tt = 0.0;
            #pragma unroll
            for (int p = 0; p < 4; ++p) {
                float4 ev = ep[p * 64 + lane];
                float p0 = ev.x * ev.x, p1 = ev.y * ev.y, p2 = ev.z * ev.z, p3 = ev.w * ev.w;
                ys += (double)p0 + (double)p1 + (double)p2 + (double)p3;
                tt += (double)zreg[p * 4 + 0] * (double)ev.x
                    + (double)zreg[p * 4 + 1] * (double)ev.y
                    + (double)zreg[p * 4 + 2] * (double)ev.z
                    + (double)zreg[p * 4 + 3] * (double)ev.w;
            }
            ys = wredd(ys);
            tt = wredd(tt);
            float y32 = (float)ys;
            float t32 = (float)tt;
            double dex = xs + ys - 2.0 * tt;
            double ud = ulp32_of(dex);
            double D = rint((double)y32 / uS) * uS - rint(2.0 * (double)t32 / ud) * ud;
            if (D < bD || (D == bD && cdx < bi)) { bD = D; bi = cdx; }
        }
        best = bi;
    }
    if (lane == 0) { fidx[r] = best; out[OUT_IDX + r] = (float)best; }
}

// ============ 4) new_ema_w = 0.99*ema_w ============
__global__ void init_ema(const float* __restrict__ emaw, float* __restrict__ out) {
    int i = blockIdx.x * blockDim.x + threadIdx.x;
    int stride = gridDim.x * blockDim.x;
    for (; i < KCODE * D2; i += stride) out[OUT_NEMA + i] = DECAYF * emaw[i];
}

// ============ 5) scatter counts + 0.01*z into new_ema_w ============
__global__ __launch_bounds__(256) void scatter(
    const float* __restrict__ zr, const float* __restrict__ zi,
    const int* __restrict__ fidx, int* __restrict__ nint, float* __restrict__ out)
{
    int wave = threadIdx.x >> 6, lane = threadIdx.x & 63;
    int r = blockIdx.x * 4 + wave;
    int idx = fidx[r];
    if (lane == 0) atomicAdd(nint + idx, 1);
    float* dst = out + OUT_NEMA + (size_t)idx * 1024;
    #pragma unroll
    for (int p = 0; p < 4; ++p) {
        int d4 = p * 64 + lane;
        const float4* zp = (d4 < 128) ? (const float4*)(zr + (size_t)r * 512)
                                      : ((const float4*)(zi + (size_t)r * 512) - 128);
        float4 zv = zp[d4];
        atomicAdd(dst + d4 * 4 + 0, OMD * zv.x);
        atomicAdd(dst + d4 * 4 + 1, OMD * zv.y);
        atomicAdd(dst + d4 * 4 + 2, OMD * zv.z);
        atomicAdd(dst + d4 * 4 + 3, OMD * zv.w);
    }
}

// ============ 6) new_w = clip(new_ema_w / cs) ============
__global__ void finalize_w(const float* __restrict__ emacs, const int* __restrict__ nint,
                           float* __restrict__ out) {
    int i = blockIdx.x * blockDim.x + threadIdx.x;
    int stride = gridDim.x * blockDim.x;
    for (; i < KCODE * D2; i += stride) {
        int k = i >> 10;
        float ncs = DECAYF * emacs[k] + OMD * (float)nint[k];
        float cs = ncs + 1e-5f;
        if (cs < 1.f) cs += 1.f;
        float w = out[OUT_NEMA + i] / cs;
        w = fminf(fmaxf(w, -5.f), 5.f);
        out[OUT_NEWW + i] = w;
    }
}

// ============ 7) new_cluster_size + entropy partial ============
__global__ __launch_bounds__(256) void cluster_fin(const float* __restrict__ emacs,
                                                   const int* __restrict__ nint,
                                                   float* __restrict__ out,
                                                   float* __restrict__ entacc) {
    int k = blockIdx.x * 256 + threadIdx.x;
    float n = (float)nint[k];
    float ncs = DECAYF * emacs[k] + OMD * n;
    out[OUT_NCS + k] = ncs;
    float p = n / 32768.f;
    float term = -p * logf(p + 1e-10f);
    __shared__ float red[256];
    red[threadIdx.x] = term;
    __syncthreads();
    for (int s = 128; s > 0; s >>= 1) {
        if (threadIdx.x < s) red[threadIdx.x] += red[threadIdx.x + s];
        __syncthreads();
    }
    if (threadIdx.x == 0) atomicAdd(entacc, red[0]);
}

__global__ void ent_fin(const float* __restrict__ entacc, float* __restrict__ out) {
    if (threadIdx.x == 0) out[OUT_ENT] = entacc[0] / logf(8192.f);
}

// ============ 8) z_q gather + loss ============
__global__ __launch_bounds__(256) void zq_loss(
    const float* __restrict__ zr, const float* __restrict__ zi,
    const float* __restrict__ emb, const int* __restrict__ fidx, float* __restrict__ out)
{
    int wave = threadIdx.x >> 6, lane = threadIdx.x & 63;
    int r = blockIdx.x * 4 + wave;
    int idx = fidx[r];
    const float4* ep = (const float4*)(emb + (size_t)idx * 1024);
    float acc = 0.f;
    #pragma unroll
    for (int p = 0; p < 4; ++p) {
        int d4 = p * 64 + lane;
        const float4* zp = (d4 < 128) ? (const float4*)(zr + (size_t)r * 512)
                                      : ((const float4*)(zi + (size_t)r * 512) - 128);
        float4 zv = zp[d4];
        float4 ev = ep[d4];
        float dx = ev.x - zv.x; acc += dx * dx;
        float dy = ev.y - zv.y; acc += dy * dy;
        float dz = ev.z - zv.z; acc += dz * dz;
        float dw = ev.w - zv.w; acc += dw * dw;
        float4* op = (d4 < 128) ? (float4*)(out + OUT_ZQR + (size_t)r * 512)
                                : ((float4*)(out + OUT_ZQI + (size_t)r * 512) - 128);
        op[d4] = ev;
    }
    acc = wredf(acc);
    if (lane == 0) out[OUT_LOSS + r] = 0.25f * acc * (1.f / 1024.f);
}

// ============ launcher ============
extern "C" void kernel_launch(void* const* d_in, const int* in_sizes, int n_in,
                              void* d_out, int out_size, void* d_ws, size_t ws_size,
                              hipStream_t stream)
{
    const float* zr    = (const float*)d_in[0];
    const float* zi    = (const float*)d_in[1];
    const float* emb   = (const float*)d_in[2];
    const float* emacs = (const float*)d_in[3];
    const float* emaw  = (const float*)d_in[4];
    float* out = (float*)d_out;
    char* ws = (char*)d_ws;

    char*  emb8   = (char*)(ws + WS_EMB8);
    float* ysq    = (float*)(ws + WS_YSQ);
    int*   nint   = (int*)(ws + WS_NINT);
    float* entacc = (float*)(ws + WS_ENT);
    int*   ccount = (int*)(ws + WS_CCOUNT);
    int*   cand   = (int*)(ws + WS_CAND);
    int*   fidx   = (int*)(ws + WS_FIDX);
    long long* pairs = (long long*)out;   // scratch inside z_q_r region (67MB; uses 33.5MB)

    hipMemsetAsync(ws + WS_NINT, 0, WS_CAND - WS_NINT, stream);  // nint + ent + ccount

    prep_emb   <<<2048, 256, 0, stream>>>(emb, emb8, ysq);
    argmin_gemm<<<512,  256, 0, stream>>>(zr, zi, emb8, ysq, pairs);
    merge_rows <<<8192, 256, 0, stream>>>(pairs, cand, ccount);
    cleanup    <<<8192, 256, 0, stream>>>(zr, zi, emb, cand, ccount, fidx, out);
    init_ema   <<<2048, 256, 0, stream>>>(emaw, out);
    scatter    <<<8192, 256, 0, stream>>>(zr, zi, fidx, nint, out);
    finalize_w <<<2048, 256, 0, stream>>>(emacs, nint, out);
    cluster_fin<<<32,   256, 0, stream>>>(emacs, nint, out, entacc);
    ent_fin    <<<1,    64,  0, stream>>>(entacc, out);
    zq_loss    <<<8192, 256, 0, stream>>>(zr, zi, emb, fidx, out);
}

// Round 5
// 603.786 us; speedup vs baseline: 2.9751x; 1.5785x over previous
//
#include <hip/hip_runtime.h>
#include <hip/hip_bf16.h>

// ---------------- problem constants ----------------
#define NROWS 32768
#define DIM   512
#define D2    1024
#define KCODE 8192
#define DECAYF 0.99f
#define OMD    0.01f
#define MARGIN 0.30f
#define CANDCAP 16
#define ZMAX 6.0f
#define IRANGE 0.04419417382415922f   // 1/sqrt(512)

typedef __attribute__((ext_vector_type(4))) float f32x4;
typedef __attribute__((ext_vector_type(4))) int   v4i;
typedef __attribute__((ext_vector_type(16))) int  i32x16;

// ---------------- workspace layout (bytes) ----------------
#define WS_EMB8    0u            // K*1024 i8  =  8,388,608 B
#define WS_YSQ     8388608u      // K f32      =     32,768 B
#define WS_NINT    8421376u      // K int      =     32,768 B
#define WS_ENT     8454144u      // 16 B
#define WS_CCOUNT  8454160u      // N int      =    131,072 B
#define WS_CAND    8585232u      // N*16 int   =  2,097,152 B
#define WS_FIDX    10682384u     // N int      =    131,072 B
#define WS_OFF     10813456u     // K int      =     32,768 B
#define WS_CUR     10846224u     // K int      =     32,768 B
#define WS_ROWLIST 10878992u     // N int      =    131,072 B

// ---------------- output layout (f32 elements, return order) ----------------
#define OUT_ZQR  0
#define OUT_ZQI  16777216
#define OUT_LOSS 33554432
#define OUT_IDX  33587200
#define OUT_ENT  33619968
#define OUT_NEWW 33619969
#define OUT_NCS  42008577
#define OUT_NEMA 42016769
// pairs scratch: 32768 rows x 128 slots x 8B = 33.5MB, lives in OUT_ZQR region
// (dead until zq_loss, which runs after merge_rows consumed pairs).

__device__ __forceinline__ float wredf(float v) {
    #pragma unroll
    for (int o = 32; o > 0; o >>= 1) v += __shfl_down(v, o, 64);
    return v;
}

__device__ __forceinline__ double wredd(double v) {
    #pragma unroll
    for (int o = 32; o > 0; o >>= 1) v += __shfl_down(v, o, 64);
    return __shfl(v, 0, 64);
}

// ULP of float32 at magnitude v (v normal, positive)
__device__ __forceinline__ double ulp32_of(double v) {
    return scalbn(1.0, ilogb(v) - 23);
}

// async global->LDS, 16B per lane; LDS dest = wave-uniform base + lane*16
__device__ __forceinline__ void gload_lds16(const void* g, void* l) {
    __builtin_amdgcn_global_load_lds(
        (const __attribute__((address_space(1))) unsigned int*)(g),
        (__attribute__((address_space(3))) unsigned int*)(l), 16, 0, 0);
}

// quantize 4 floats -> 4 packed i8 (byte0 = x)
__device__ __forceinline__ int q4(float4 v, float s) {
    int a = (int)rintf(fminf(fmaxf(v.x * s, -127.f), 127.f));
    int b = (int)rintf(fminf(fmaxf(v.y * s, -127.f), 127.f));
    int c = (int)rintf(fminf(fmaxf(v.z * s, -127.f), 127.f));
    int d = (int)rintf(fminf(fmaxf(v.w * s, -127.f), 127.f));
    return (a & 255) | ((b & 255) << 8) | ((c & 255) << 16) | ((d & 255) << 24);
}

// ============ 1) y_sq + emb -> i8 ============
__global__ __launch_bounds__(256) void prep_emb(const float* __restrict__ emb,
                                                char* __restrict__ emb8,
                                                float* __restrict__ ysq) {
    int wave = threadIdx.x >> 6, lane = threadIdx.x & 63;
    int k = blockIdx.x * 4 + wave;
    const float4* src = (const float4*)(emb + (size_t)k * D2);
    v4i* dst = (v4i*)(emb8 + (size_t)k * D2);
    const float es = 127.0f / IRANGE;
    float s = 0.f;
    float4 v0 = src[lane * 4 + 0];
    float4 v1 = src[lane * 4 + 1];
    float4 v2 = src[lane * 4 + 2];
    float4 v3 = src[lane * 4 + 3];
    s += v0.x*v0.x + v0.y*v0.y + v0.z*v0.z + v0.w*v0.w;
    s += v1.x*v1.x + v1.y*v1.y + v1.z*v1.z + v1.w*v1.w;
    s += v2.x*v2.x + v2.y*v2.y + v2.z*v2.z + v2.w*v2.w;
    s += v3.x*v3.x + v3.y*v3.y + v3.z*v3.z + v3.w*v3.w;
    v4i pk; pk[0] = q4(v0, es); pk[1] = q4(v1, es); pk[2] = q4(v2, es); pk[3] = q4(v3, es);
    dst[lane] = pk;
    s = wredf(s);
    if (lane == 0) ysq[k] = s;
}

// ============ 2) i8 MFMA approx-score, A(32 rows/wave, full K) in 128 regs ============
__global__ __launch_bounds__(256, 2) void argmin_gemm(
    const float* __restrict__ zr, const float* __restrict__ zi,
    const char* __restrict__ emb8, const float* __restrict__ ysq,
    long long* __restrict__ pairs)
{
    __shared__ char bufs[2][16384];   // 2 x 16KB halves
    const int tid  = threadIdx.x;
    const int wave = tid >> 6, lane = tid & 63;
    const int colc = lane & 31;      // A row / B col index
    const int hh   = lane >> 5;      // k-subgroup
    const int rowblk = blockIdx.x >> 1;
    const int slice  = blockIdx.x & 1;

    // ---- A fragments: 32 rows/wave, full K=1024, i8, 128 VGPR ----
    const int arow = rowblk * 128 + wave * 32 + colc;
    const float zs = 127.0f / ZMAX;
    const float* zrp = zr + (size_t)arow * 512 + hh * 16;
    const float* zip = zi + (size_t)arow * 512 + hh * 16;
    v4i afrag[32];
    #pragma unroll
    for (int ft = 0; ft < 16; ++ft) {
        const float4* p = (const float4*)(zrp + ft * 32);
        v4i a; a[0] = q4(p[0], zs); a[1] = q4(p[1], zs); a[2] = q4(p[2], zs); a[3] = q4(p[3], zs);
        afrag[ft] = a;
    }
    #pragma unroll
    for (int ft = 0; ft < 16; ++ft) {
        const float4* p = (const float4*)(zip + ft * 32);
        v4i a; a[0] = q4(p[0], zs); a[1] = q4(p[1], zs); a[2] = q4(p[2], zs); a[3] = q4(p[3], zs);
        afrag[16 + ft] = a;
    }

    // per-lane per-row top-2 (sorted v0<=v1), chunk ids packed 2x8b
    float tv0[16], tv1[16];
    int cpk[16];
    #pragma unroll
    for (int g = 0; g < 16; ++g) { tv0[g] = 3.4e38f; tv1[g] = 3.4e38f; cpk[g] = 0; }

    const char* gslice = emb8 + (size_t)slice * 4096 * 1024;
    const float* yslice = ysq + slice * 4096;

    // stage half (chunk_, h_): 32 codes x 512 depth i8 = 16KB, swizzled source
#define STAGE(dstbuf, chunk_, h_) do {                                           \
        const char* gb = gslice + ((size_t)(chunk_) * 32 * 1024 + (size_t)(h_) * 512); \
        _Pragma("unroll")                                                        \
        for (int p = 0; p < 4; ++p) {                                            \
            int s_ = p * 4096 + wave * 1024 + lane * 16;                         \
            int code_ = s_ >> 9;                                                 \
            int c16p_ = (s_ & 511) >> 4;                                         \
            gload_lds16(gb + (size_t)code_ * 1024 + ((c16p_ ^ (code_ & 7)) << 4), \
                        &(dstbuf)[p * 4096 + wave * 1024]);                      \
        }                                                                        \
    } while (0)

    const char* bb0 = &bufs[0][0] + colc * 512;
    const char* bb1 = &bufs[1][0] + colc * 512;
    const int bxor = colc & 7;
    const float sfac = 2.0f * (ZMAX / 127.0f) * (IRANGE / 127.0f);

    STAGE(bufs[0], 0, 0);
    __syncthreads();

    for (int c = 0; c < 128; ++c) {
        STAGE(bufs[1], c, 1);
        i32x16 acc0, acc1;
        #pragma unroll
        for (int g = 0; g < 16; ++g) { acc0[g] = 0; acc1[g] = 0; }
        #pragma unroll
        for (int kt = 0; kt < 16; kt += 2) {
            v4i b0 = *(const v4i*)(bb0 + ((((kt    ) * 2 + hh) ^ bxor) << 4));
            v4i b1 = *(const v4i*)(bb0 + ((((kt + 1) * 2 + hh) ^ bxor) << 4));
            acc0 = __builtin_amdgcn_mfma_i32_32x32x32_i8(afrag[kt],     b0, acc0, 0, 0, 0);
            acc1 = __builtin_amdgcn_mfma_i32_32x32x32_i8(afrag[kt + 1], b1, acc1, 0, 0, 0);
        }
        __syncthreads();

        if (c + 1 < 128) STAGE(bufs[0], c + 1, 0);
        #pragma unroll
        for (int kt = 0; kt < 16; kt += 2) {
            v4i b0 = *(const v4i*)(bb1 + ((((kt    ) * 2 + hh) ^ bxor) << 4));
            v4i b1 = *(const v4i*)(bb1 + ((((kt + 1) * 2 + hh) ^ bxor) << 4));
            acc0 = __builtin_amdgcn_mfma_i32_32x32x32_i8(afrag[16 + kt],     b0, acc0, 0, 0, 0);
            acc1 = __builtin_amdgcn_mfma_i32_32x32x32_i8(afrag[16 + kt + 1], b1, acc1, 0, 0, 0);
        }
        float ysv = yslice[c * 32 + colc];
        #pragma unroll
        for (int g = 0; g < 16; ++g) {
            float fdot = (float)(acc0[g] + acc1[g]);
            float sc = fmaf(-sfac, fdot, ysv);
            if (sc < tv1[g]) {
                bool b0 = sc < tv0[g];
                int cp = cpk[g];
                cpk[g] = b0 ? (((cp & 0xFF) << 8) | c) : ((cp & 0xFF) | (c << 8));
                float ov0 = tv0[g];
                tv1[g] = b0 ? ov0 : sc;
                tv0[g] = b0 ? sc : ov0;
            }
        }
        __syncthreads();
    }
#undef STAGE

    // ---- write per-lane top-2 to pair buffer: pairs[row][slice*64 + col*2 + t] ----
    #pragma unroll
    for (int g = 0; g < 16; ++g) {
        int rloc = (g & 3) + 8 * (g >> 2) + 4 * hh;       // C/D row mapping (m74/m101)
        int rowg = rowblk * 128 + wave * 32 + rloc;
        size_t base = (size_t)rowg * 128 + slice * 64 + colc * 2;
        int cp = cpk[g];
        int code0 = slice * 4096 + (cp & 0xFF) * 32 + colc;
        int code1 = slice * 4096 + ((cp >> 8) & 0xFF) * 32 + colc;
        pairs[base + 0] = ((long long)(unsigned)code0 << 32) | (unsigned)__float_as_uint(tv0[g]);
        pairs[base + 1] = ((long long)(unsigned)code1 << 32) | (unsigned)__float_as_uint(tv1[g]);
    }
}

// ============ 2b) per-row merge of 128 pair slots -> candidate list ============
__global__ __launch_bounds__(256) void merge_rows(const long long* __restrict__ pairs,
                                                  int* __restrict__ cand,
                                                  int* __restrict__ ccount)
{
    int wave = threadIdx.x >> 6, lane = threadIdx.x & 63;
    int row = blockIdx.x * 4 + wave;
    const long long* pr = pairs + (size_t)row * 128;
    long long p0 = pr[lane];
    long long p1 = pr[64 + lane];
    float v0v = __uint_as_float((unsigned)p0);
    int   i0  = (int)(p0 >> 32);
    float v1v = __uint_as_float((unsigned)p1);
    int   i1  = (int)(p1 >> 32);
    float m = fminf(v0v, v1v);
    #pragma unroll
    for (int o = 32; o > 0; o >>= 1) m = fminf(m, __shfl_xor(m, o, 64));
    float lim = m + MARGIN;
    unsigned long long m0 = __ballot(v0v < lim);
    unsigned long long m1 = __ballot(v1v < lim);
    int t0 = __popcll(m0);
    int cnt = t0 + __popcll(m1);
    if (cnt > CANDCAP) cnt = CANDCAP;
    unsigned long long below = (lane == 63) ? 0xFFFFFFFFFFFFFFFFull >> 1
                                            : ((1ull << lane) - 1);
    if (v0v < lim) {
        int pos = __popcll(m0 & below);
        if (pos < CANDCAP) cand[(size_t)row * CANDCAP + pos] = i0;
    }
    if (v1v < lim) {
        int pos = t0 + __popcll(m1 & below);
        if (pos < CANDCAP) cand[(size_t)row * CANDCAP + pos] = i1;
    }
    if (lane == 0) ccount[row] = cnt;
}

// ============ 3) rescore mimicking numpy's f32 pipeline (+ histogram) ============
__global__ __launch_bounds__(256) void cleanup(
    const float* __restrict__ zr, const float* __restrict__ zi,
    const float* __restrict__ emb, const int* __restrict__ cand,
    const int* __restrict__ ccount, int* __restrict__ fidx,
    int* __restrict__ nint, float* __restrict__ out)
{
    int wave = threadIdx.x >> 6, lane = threadIdx.x & 63;
    int r = blockIdx.x * 4 + wave;
    int cnt = ccount[r];
    int best = cand[r * CANDCAP];
    if (cnt > 1) {
        float zreg[16];
        double xs = 0.0;
        #pragma unroll
        for (int p = 0; p < 4; ++p) {
            int d4 = p * 64 + lane;
            const float4* zp = (d4 < 128) ? (const float4*)(zr + (size_t)r * 512)
                                          : ((const float4*)(zi + (size_t)r * 512) - 128);
            float4 zv = zp[d4];
            zreg[p * 4 + 0] = zv.x; zreg[p * 4 + 1] = zv.y;
            zreg[p * 4 + 2] = zv.z; zreg[p * 4 + 3] = zv.w;
            xs += (double)zv.x * zv.x + (double)zv.y * zv.y
                + (double)zv.z * zv.z + (double)zv.w * zv.w;
        }
        xs = wredd(xs);
        double uS = ulp32_of(xs);

        double bD = 1e300; int bi = 1 << 30;
        for (int i = 0; i < cnt; ++i) {
            int cdx = cand[r * CANDCAP + i];
            const float4* ep = (const float4*)(emb + (size_t)cdx * 1024);
            double ys = 0.0, tt = 0.0;
            #pragma unroll
            for (int p = 0; p < 4; ++p) {
                float4 ev = ep[p * 64 + lane];
                float p0 = ev.x * ev.x, p1 = ev.y * ev.y, p2 = ev.z * ev.z, p3 = ev.w * ev.w;
                ys += (double)p0 + (double)p1 + (double)p2 + (double)p3;
                tt += (double)zreg[p * 4 + 0] * (double)ev.x
                    + (double)zreg[p * 4 + 1] * (double)ev.y
                    + (double)zreg[p * 4 + 2] * (double)ev.z
                    + (double)zreg[p * 4 + 3] * (double)ev.w;
            }
            ys = wredd(ys);
            tt = wredd(tt);
            float y32 = (float)ys;
            float t32 = (float)tt;
            double dex = xs + ys - 2.0 * tt;
            double ud = ulp32_of(dex);
            double D = rint((double)y32 / uS) * uS - rint(2.0 * (double)t32 / ud) * ud;
            if (D < bD || (D == bD && cdx < bi)) { bD = D; bi = cdx; }
        }
        best = bi;
    }
    if (lane == 0) {
        fidx[r] = best;
        out[OUT_IDX + r] = (float)best;
        atomicAdd(nint + best, 1);
    }
}

// ============ 4) exclusive prefix sum over K=8192 bucket counts ============
__global__ __launch_bounds__(256) void scan_codes(const int* __restrict__ nint,
                                                  int* __restrict__ off,
                                                  int* __restrict__ cur) {
    __shared__ int part[256];
    int tid = threadIdx.x;
    int base = tid * 32;
    int loc[32];
    int s = 0;
    #pragma unroll
    for (int j = 0; j < 32; ++j) { loc[j] = s; s += nint[base + j]; }
    part[tid] = s;
    __syncthreads();
    // Hillis-Steele inclusive scan over 256 partials
    for (int o = 1; o < 256; o <<= 1) {
        int t = (tid >= o) ? part[tid - o] : 0;
        __syncthreads();
        part[tid] += t;
        __syncthreads();
    }
    int excl = part[tid] - s;
    #pragma unroll
    for (int j = 0; j < 32; ++j) {
        off[base + j] = excl + loc[j];
        cur[base + j] = 0;
    }
}

// ============ 5) bucket fill: rowlist grouped by assigned code ============
__global__ __launch_bounds__(256) void fill_rows(const int* __restrict__ fidx,
                                                 const int* __restrict__ off,
                                                 int* __restrict__ cur,
                                                 int* __restrict__ rowlist) {
    int r = blockIdx.x * 256 + threadIdx.x;
    int idx = fidx[r];
    int pos = atomicAdd(cur + idx, 1);
    rowlist[off[idx] + pos] = r;
}

// ============ 6) fused EMA tail: one block per code ============
// new_ema_w = 0.99*ema_w + 0.01*sum(z rows); new_w = clip(new_ema_w/cs);
// new_cluster_size; entropy partial. No f32 atomics on the big arrays.
__global__ __launch_bounds__(256) void ema_update(
    const float* __restrict__ zr, const float* __restrict__ zi,
    const float* __restrict__ emaw, const float* __restrict__ emacs,
    const int* __restrict__ nint, const int* __restrict__ off,
    const int* __restrict__ rowlist, float* __restrict__ out,
    float* __restrict__ entacc)
{
    int k = blockIdx.x;
    int tid = threadIdx.x;
    int cnt = nint[k];
    int o0 = off[k];
    float ax = 0.f, ay = 0.f, az = 0.f, aw = 0.f;
    for (int i = 0; i < cnt; ++i) {
        int r = rowlist[o0 + i];
        float4 zv = (tid < 128) ? ((const float4*)(zr + (size_t)r * 512))[tid]
                                : ((const float4*)(zi + (size_t)r * 512))[tid - 128];
        ax += zv.x; ay += zv.y; az += zv.z; aw += zv.w;
    }
    float4 ew = ((const float4*)(emaw + (size_t)k * 1024))[tid];
    float4 nem;
    nem.x = DECAYF * ew.x + OMD * ax;
    nem.y = DECAYF * ew.y + OMD * ay;
    nem.z = DECAYF * ew.z + OMD * az;
    nem.w = DECAYF * ew.w + OMD * aw;
    ((float4*)(out + OUT_NEMA + (size_t)k * 1024))[tid] = nem;
    float ncs = DECAYF * emacs[k] + OMD * (float)cnt;
    float cs = ncs + 1e-5f;
    if (cs < 1.f) cs += 1.f;
    float inv = 1.f / cs;
    float4 w;
    w.x = fminf(fmaxf(nem.x * inv, -5.f), 5.f);
    w.y = fminf(fmaxf(nem.y * inv, -5.f), 5.f);
    w.z = fminf(fmaxf(nem.z * inv, -5.f), 5.f);
    w.w = fminf(fmaxf(nem.w * inv, -5.f), 5.f);
    ((float4*)(out + OUT_NEWW + (size_t)k * 1024))[tid] = w;
    if (tid == 0) {
        out[OUT_NCS + k] = ncs;
        float p = (float)cnt / 32768.f;
        atomicAdd(entacc, -p * logf(p + 1e-10f));
    }
}

__global__ void ent_fin(const float* __restrict__ entacc, float* __restrict__ out) {
    if (threadIdx.x == 0) out[OUT_ENT] = entacc[0] / logf(8192.f);
}

// ============ 7) z_q gather + loss ============
__global__ __launch_bounds__(256) void zq_loss(
    const float* __restrict__ zr, const float* __restrict__ zi,
    const float* __restrict__ emb, const int* __restrict__ fidx, float* __restrict__ out)
{
    int wave = threadIdx.x >> 6, lane = threadIdx.x & 63;
    int r = blockIdx.x * 4 + wave;
    int idx = fidx[r];
    const float4* ep = (const float4*)(emb + (size_t)idx * 1024);
    float acc = 0.f;
    #pragma unroll
    for (int p = 0; p < 4; ++p) {
        int d4 = p * 64 + lane;
        const float4* zp = (d4 < 128) ? (const float4*)(zr + (size_t)r * 512)
                                      : ((const float4*)(zi + (size_t)r * 512) - 128);
        float4 zv = zp[d4];
        float4 ev = ep[d4];
        float dx = ev.x - zv.x; acc += dx * dx;
        float dy = ev.y - zv.y; acc += dy * dy;
        float dz = ev.z - zv.z; acc += dz * dz;
        float dw = ev.w - zv.w; acc += dw * dw;
        float4* op = (d4 < 128) ? (float4*)(out + OUT_ZQR + (size_t)r * 512)
                                : ((float4*)(out + OUT_ZQI + (size_t)r * 512) - 128);
        op[d4] = ev;
    }
    acc = wredf(acc);
    if (lane == 0) out[OUT_LOSS + r] = 0.25f * acc * (1.f / 1024.f);
}

// ============ launcher ============
extern "C" void kernel_launch(void* const* d_in, const int* in_sizes, int n_in,
                              void* d_out, int out_size, void* d_ws, size_t ws_size,
                              hipStream_t stream)
{
    const float* zr    = (const float*)d_in[0];
    const float* zi    = (const float*)d_in[1];
    const float* emb   = (const float*)d_in[2];
    const float* emacs = (const float*)d_in[3];
    const float* emaw  = (const float*)d_in[4];
    float* out = (float*)d_out;
    char* ws = (char*)d_ws;

    char*  emb8    = (char*)(ws + WS_EMB8);
    float* ysq     = (float*)(ws + WS_YSQ);
    int*   nint    = (int*)(ws + WS_NINT);
    float* entacc  = (float*)(ws + WS_ENT);
    int*   ccount  = (int*)(ws + WS_CCOUNT);
    int*   cand    = (int*)(ws + WS_CAND);
    int*   fidx    = (int*)(ws + WS_FIDX);
    int*   off     = (int*)(ws + WS_OFF);
    int*   cur     = (int*)(ws + WS_CUR);
    int*   rowlist = (int*)(ws + WS_ROWLIST);
    long long* pairs = (long long*)out;   // scratch inside z_q_r region

    hipMemsetAsync(ws + WS_NINT, 0, 32768 + 16, stream);   // nint + entacc

    prep_emb   <<<2048, 256, 0, stream>>>(emb, emb8, ysq);
    argmin_gemm<<<512,  256, 0, stream>>>(zr, zi, emb8, ysq, pairs);
    merge_rows <<<8192, 256, 0, stream>>>(pairs, cand, ccount);
    cleanup    <<<8192, 256, 0, stream>>>(zr, zi, emb, cand, ccount, fidx, nint, out);
    scan_codes <<<1,    256, 0, stream>>>(nint, off, cur);
    fill_rows  <<<128,  256, 0, stream>>>(fidx, off, cur, rowlist);
    ema_update <<<8192, 256, 0, stream>>>(zr, zi, emaw, emacs, nint, off, rowlist, out, entacc);
    ent_fin    <<<1,    64,  0, stream>>>(entacc, out);
    zq_loss    <<<8192, 256, 0, stream>>>(zr, zi, emb, fidx, out);
}

// Round 6
// 587.889 us; speedup vs baseline: 3.0556x; 1.0270x over previous
//
#include <hip/hip_runtime.h>
#include <hip/hip_bf16.h>

// ---------------- problem constants ----------------
#define NROWS 32768
#define DIM   512
#define D2    1024
#define KCODE 8192
#define DECAYF 0.99f
#define OMD    0.01f
#define MARGIN 0.30f
#define CANDCAP 16
#define ZMAX 6.0f
#define IRANGE 0.04419417382415922f   // 1/sqrt(512)

typedef __attribute__((ext_vector_type(4))) float f32x4;
typedef __attribute__((ext_vector_type(4))) int   v4i;
typedef __attribute__((ext_vector_type(16))) int  i32x16;

// ---------------- workspace layout (bytes) ----------------
// emb8t: transposed codebook, per 32-code chunk: [64 slots][32 codes][16B] = 32KB
#define WS_EMB8T   0u            // 256 chunks * 32768 = 8,388,608 B
#define WS_YSQ     8388608u      // K f32      =     32,768 B
#define WS_NINT    8421376u      // K int      =     32,768 B
#define WS_ENT     8454144u      // 16 B
#define WS_CCOUNT  8454160u      // N int      =    131,072 B
#define WS_CAND    8585232u      // N*16 int   =  2,097,152 B
#define WS_FIDX    10682384u     // N int      =    131,072 B
#define WS_OFF     10813456u     // K int      =     32,768 B
#define WS_CUR     10846224u     // K int      =     32,768 B
#define WS_ROWLIST 10878992u     // N int      =    131,072 B

// ---------------- output layout (f32 elements, return order) ----------------
#define OUT_ZQR  0
#define OUT_ZQI  16777216
#define OUT_LOSS 33554432
#define OUT_IDX  33587200
#define OUT_ENT  33619968
#define OUT_NEWW 33619969
#define OUT_NCS  42008577
#define OUT_NEMA 42016769
// pairs scratch: 32768 rows x 128 slots x 8B = 33.5MB, lives in OUT_ZQR region
// (dead until zq_loss, which runs after merge_rows consumed pairs).

__device__ __forceinline__ float wredf(float v) {
    #pragma unroll
    for (int o = 32; o > 0; o >>= 1) v += __shfl_down(v, o, 64);
    return v;
}

__device__ __forceinline__ double wredd(double v) {
    #pragma unroll
    for (int o = 32; o > 0; o >>= 1) v += __shfl_down(v, o, 64);
    return __shfl(v, 0, 64);
}

// ULP of float32 at magnitude v (v normal, positive)
__device__ __forceinline__ double ulp32_of(double v) {
    return scalbn(1.0, ilogb(v) - 23);
}

// async global->LDS, 16B per lane; LDS dest = wave-uniform base + lane*16
__device__ __forceinline__ void gload_lds16(const void* g, void* l) {
    __builtin_amdgcn_global_load_lds(
        (const __attribute__((address_space(1))) unsigned int*)(g),
        (__attribute__((address_space(3))) unsigned int*)(l), 16, 0, 0);
}

// quantize 4 floats -> 4 packed i8 (byte0 = x)
__device__ __forceinline__ int q4(float4 v, float s) {
    int a = (int)rintf(fminf(fmaxf(v.x * s, -127.f), 127.f));
    int b = (int)rintf(fminf(fmaxf(v.y * s, -127.f), 127.f));
    int c = (int)rintf(fminf(fmaxf(v.z * s, -127.f), 127.f));
    int d = (int)rintf(fminf(fmaxf(v.w * s, -127.f), 127.f));
    return (a & 255) | ((b & 255) << 8) | ((c & 255) << 16) | ((d & 255) << 24);
}

// ============ 1) y_sq + emb -> i8 transposed chunk layout ============
// emb8t[(k>>5)*32768 + slot*512 + (k&31)*16], slot = 16B K-segment (0..63)
__global__ __launch_bounds__(256) void prep_emb(const float* __restrict__ emb,
                                                char* __restrict__ emb8t,
                                                float* __restrict__ ysq) {
    int wave = threadIdx.x >> 6, lane = threadIdx.x & 63;
    int k = blockIdx.x * 4 + wave;
    const float4* src = (const float4*)(emb + (size_t)k * D2);
    const float es = 127.0f / IRANGE;
    float s = 0.f;
    float4 v0 = src[lane * 4 + 0];
    float4 v1 = src[lane * 4 + 1];
    float4 v2 = src[lane * 4 + 2];
    float4 v3 = src[lane * 4 + 3];
    s += v0.x*v0.x + v0.y*v0.y + v0.z*v0.z + v0.w*v0.w;
    s += v1.x*v1.x + v1.y*v1.y + v1.z*v1.z + v1.w*v1.w;
    s += v2.x*v2.x + v2.y*v2.y + v2.z*v2.z + v2.w*v2.w;
    s += v3.x*v3.x + v3.y*v3.y + v3.z*v3.z + v3.w*v3.w;
    v4i pk; pk[0] = q4(v0, es); pk[1] = q4(v1, es); pk[2] = q4(v2, es); pk[3] = q4(v3, es);
    v4i* dst = (v4i*)(emb8t + (size_t)(k >> 5) * 32768 + (size_t)lane * 512 + (k & 31) * 16);
    *dst = pk;
    s = wredf(s);
    if (lane == 0) ysq[k] = s;
}

// ============ 2) i8 MFMA approx-score, transposed LDS (conflict-free) ============
// Grid 512 = 256 row-blocks x 2 code-slices. Block: 4 waves, 128 rows, 4096 codes.
// Chunk = 32 codes staged as one 32KB linear copy; double-buffered (2x32KB LDS);
// ONE barrier per chunk. Compute read: lds + m*1024 + hh*512 + colc*16 -> each
// half-wave reads 512B contiguous = zero bank conflicts, immediate offsets.
__global__ __launch_bounds__(256, 2) void argmin_gemm(
    const float* __restrict__ zr, const float* __restrict__ zi,
    const char* __restrict__ emb8t, const float* __restrict__ ysq,
    long long* __restrict__ pairs)
{
    __shared__ char bufs[2][32768];
    const int tid  = threadIdx.x;
    const int wave = tid >> 6, lane = tid & 63;
    const int colc = lane & 31;      // A row / B col index
    const int hh   = lane >> 5;      // k-subgroup
    const int rowblk = blockIdx.x >> 1;
    const int slice  = blockIdx.x & 1;

    // ---- A fragments: 32 rows/wave, full K=1024, i8, 128 VGPR ----
    const int arow = rowblk * 128 + wave * 32 + colc;
    const float zs = 127.0f / ZMAX;
    const float* zrp = zr + (size_t)arow * 512 + hh * 16;
    const float* zip = zi + (size_t)arow * 512 + hh * 16;
    v4i afrag[32];
    #pragma unroll
    for (int ft = 0; ft < 16; ++ft) {
        const float4* p = (const float4*)(zrp + ft * 32);
        v4i a; a[0] = q4(p[0], zs); a[1] = q4(p[1], zs); a[2] = q4(p[2], zs); a[3] = q4(p[3], zs);
        afrag[ft] = a;
    }
    #pragma unroll
    for (int ft = 0; ft < 16; ++ft) {
        const float4* p = (const float4*)(zip + ft * 32);
        v4i a; a[0] = q4(p[0], zs); a[1] = q4(p[1], zs); a[2] = q4(p[2], zs); a[3] = q4(p[3], zs);
        afrag[16 + ft] = a;
    }

    // per-lane per-row top-2 (sorted v0<=v1), chunk ids packed 2x8b
    float tv0[16], tv1[16];
    int cpk[16];
    #pragma unroll
    for (int g = 0; g < 16; ++g) { tv0[g] = 3.4e38f; tv1[g] = 3.4e38f; cpk[g] = 0; }

    const char* gslice = emb8t + (size_t)slice * 128 * 32768;
    const float* yslice = ysq + slice * 4096;

    // stage chunk: 32KB linear copy, 8 x gload16 per wave
#define STAGE(dstbuf, chunk_) do {                                               \
        const char* gb = gslice + (size_t)(chunk_) * 32768 + wave * 8192         \
                       + (size_t)lane * 16;                                      \
        char* lb = (dstbuf) + wave * 8192;                                       \
        _Pragma("unroll")                                                        \
        for (int q = 0; q < 8; ++q)                                              \
            gload_lds16(gb + q * 1024, lb + q * 1024);                           \
    } while (0)

    const float sfac = 2.0f * (ZMAX / 127.0f) * (IRANGE / 127.0f);
    const int boff = colc * 16 + hh * 512;

    STAGE(bufs[0], 0);
    __syncthreads();

    for (int c = 0; c < 128; ++c) {
        const int cur = c & 1;
        if (c + 1 < 128) STAGE(bufs[cur ^ 1], c + 1);

        const char* bb = &bufs[cur][0] + boff;
        i32x16 acc0, acc1;
        #pragma unroll
        for (int g = 0; g < 16; ++g) { acc0[g] = 0; acc1[g] = 0; }
        #pragma unroll
        for (int m = 0; m < 32; m += 2) {
            v4i b0 = *(const v4i*)(bb + (m    ) * 1024);
            v4i b1 = *(const v4i*)(bb + (m + 1) * 1024);
            acc0 = __builtin_amdgcn_mfma_i32_32x32x32_i8(afrag[m],     b0, acc0, 0, 0, 0);
            acc1 = __builtin_amdgcn_mfma_i32_32x32x32_i8(afrag[m + 1], b1, acc1, 0, 0, 0);
        }

        float ysv = yslice[c * 32 + colc];
        #pragma unroll
        for (int g = 0; g < 16; ++g) {
            float fdot = (float)(acc0[g] + acc1[g]);
            float sc = fmaf(-sfac, fdot, ysv);
            if (sc < tv1[g]) {
                bool b0 = sc < tv0[g];
                int cp = cpk[g];
                cpk[g] = b0 ? (((cp & 0xFF) << 8) | c) : ((cp & 0xFF) | (c << 8));
                float ov0 = tv0[g];
                tv1[g] = b0 ? ov0 : sc;
                tv0[g] = b0 ? sc : ov0;
            }
        }
        __syncthreads();
    }
#undef STAGE

    // ---- write per-lane top-2 to pair buffer: pairs[row][slice*64 + col*2 + t] ----
    #pragma unroll
    for (int g = 0; g < 16; ++g) {
        int rloc = (g & 3) + 8 * (g >> 2) + 4 * hh;       // C/D row mapping (m74/m101)
        int rowg = rowblk * 128 + wave * 32 + rloc;
        size_t base = (size_t)rowg * 128 + slice * 64 + colc * 2;
        int cp = cpk[g];
        int code0 = slice * 4096 + (cp & 0xFF) * 32 + colc;
        int code1 = slice * 4096 + ((cp >> 8) & 0xFF) * 32 + colc;
        pairs[base + 0] = ((long long)(unsigned)code0 << 32) | (unsigned)__float_as_uint(tv0[g]);
        pairs[base + 1] = ((long long)(unsigned)code1 << 32) | (unsigned)__float_as_uint(tv1[g]);
    }
}

// ============ 2b) per-row merge of 128 pair slots -> candidate list ============
__global__ __launch_bounds__(256) void merge_rows(const long long* __restrict__ pairs,
                                                  int* __restrict__ cand,
                                                  int* __restrict__ ccount)
{
    int wave = threadIdx.x >> 6, lane = threadIdx.x & 63;
    int row = blockIdx.x * 4 + wave;
    const long long* pr = pairs + (size_t)row * 128;
    long long p0 = pr[lane];
    long long p1 = pr[64 + lane];
    float v0v = __uint_as_float((unsigned)p0);
    int   i0  = (int)(p0 >> 32);
    float v1v = __uint_as_float((unsigned)p1);
    int   i1  = (int)(p1 >> 32);
    float m = fminf(v0v, v1v);
    #pragma unroll
    for (int o = 32; o > 0; o >>= 1) m = fminf(m, __shfl_xor(m, o, 64));
    float lim = m + MARGIN;
    unsigned long long m0 = __ballot(v0v < lim);
    unsigned long long m1 = __ballot(v1v < lim);
    int t0 = __popcll(m0);
    int cnt = t0 + __popcll(m1);
    if (cnt > CANDCAP) cnt = CANDCAP;
    unsigned long long below = (lane == 63) ? 0xFFFFFFFFFFFFFFFFull >> 1
                                            : ((1ull << lane) - 1);
    if (v0v < lim) {
        int pos = __popcll(m0 & below);
        if (pos < CANDCAP) cand[(size_t)row * CANDCAP + pos] = i0;
    }
    if (v1v < lim) {
        int pos = t0 + __popcll(m1 & below);
        if (pos < CANDCAP) cand[(size_t)row * CANDCAP + pos] = i1;
    }
    if (lane == 0) ccount[row] = cnt;
}

// ============ 3) rescore mimicking numpy's f32 pipeline (+ histogram) ============
__global__ __launch_bounds__(256) void cleanup(
    const float* __restrict__ zr, const float* __restrict__ zi,
    const float* __restrict__ emb, const int* __restrict__ cand,
    const int* __restrict__ ccount, int* __restrict__ fidx,
    int* __restrict__ nint, float* __restrict__ out)
{
    int wave = threadIdx.x >> 6, lane = threadIdx.x & 63;
    int r = blockIdx.x * 4 + wave;
    int cnt = ccount[r];
    int best = cand[r * CANDCAP];
    if (cnt > 1) {
        float zreg[16];
        double xs = 0.0;
        #pragma unroll
        for (int p = 0; p < 4; ++p) {
            int d4 = p * 64 + lane;
            const float4* zp = (d4 < 128) ? (const float4*)(zr + (size_t)r * 512)
                                          : ((const float4*)(zi + (size_t)r * 512) - 128);
            float4 zv = zp[d4];
            zreg[p * 4 + 0] = zv.x; zreg[p * 4 + 1] = zv.y;
            zreg[p * 4 + 2] = zv.z; zreg[p * 4 + 3] = zv.w;
            xs += (double)zv.x * zv.x + (double)zv.y * zv.y
                + (double)zv.z * zv.z + (double)zv.w * zv.w;
        }
        xs = wredd(xs);
        double uS = ulp32_of(xs);

        double bD = 1e300; int bi = 1 << 30;
        for (int i = 0; i < cnt; ++i) {
            int cdx = cand[r * CANDCAP + i];
            const float4* ep = (const float4*)(emb + (size_t)cdx * 1024);
            double ys = 0.0, tt = 0.0;
            #pragma unroll
            for (int p = 0; p < 4; ++p) {
                float4 ev = ep[p * 64 + lane];
                float p0 = ev.x * ev.x, p1 = ev.y * ev.y, p2 = ev.z * ev.z, p3 = ev.w * ev.w;
                ys += (double)p0 + (double)p1 + (double)p2 + (double)p3;
                tt += (double)zreg[p * 4 + 0] * (double)ev.x
                    + (double)zreg[p * 4 + 1] * (double)ev.y
                    + (double)zreg[p * 4 + 2] * (double)ev.z
                    + (double)zreg[p * 4 + 3] * (double)ev.w;
            }
            ys = wredd(ys);
            tt = wredd(tt);
            float y32 = (float)ys;
            float t32 = (float)tt;
            double dex = xs + ys - 2.0 * tt;
            double ud = ulp32_of(dex);
            double D = rint((double)y32 / uS) * uS - rint(2.0 * (double)t32 / ud) * ud;
            if (D < bD || (D == bD && cdx < bi)) { bD = D; bi = cdx; }
        }
        best = bi;
    }
    if (lane == 0) {
        fidx[r] = best;
        out[OUT_IDX + r] = (float)best;
        atomicAdd(nint + best, 1);
    }
}

// ============ 4) exclusive prefix sum over K=8192 bucket counts ============
__global__ __launch_bounds__(256) void scan_codes(const int* __restrict__ nint,
                                                  int* __restrict__ off,
                                                  int* __restrict__ cur) {
    __shared__ int part[256];
    int tid = threadIdx.x;
    int base = tid * 32;
    int loc[32];
    int s = 0;
    #pragma unroll
    for (int j = 0; j < 32; ++j) { loc[j] = s; s += nint[base + j]; }
    part[tid] = s;
    __syncthreads();
    for (int o = 1; o < 256; o <<= 1) {
        int t = (tid >= o) ? part[tid - o] : 0;
        __syncthreads();
        part[tid] += t;
        __syncthreads();
    }
    int excl = part[tid] - s;
    #pragma unroll
    for (int j = 0; j < 32; ++j) {
        off[base + j] = excl + loc[j];
        cur[base + j] = 0;
    }
}

// ============ 5) bucket fill: rowlist grouped by assigned code ============
__global__ __launch_bounds__(256) void fill_rows(const int* __restrict__ fidx,
                                                 const int* __restrict__ off,
                                                 int* __restrict__ cur,
                                                 int* __restrict__ rowlist) {
    int r = blockIdx.x * 256 + threadIdx.x;
    int idx = fidx[r];
    int pos = atomicAdd(cur + idx, 1);
    rowlist[off[idx] + pos] = r;
}

// ============ 6) fused EMA tail: one block per code ============
__global__ __launch_bounds__(256) void ema_update(
    const float* __restrict__ zr, const float* __restrict__ zi,
    const float* __restrict__ emaw, const float* __restrict__ emacs,
    const int* __restrict__ nint, const int* __restrict__ off,
    const int* __restrict__ rowlist, float* __restrict__ out,
    float* __restrict__ entacc)
{
    int k = blockIdx.x;
    int tid = threadIdx.x;
    int cnt = nint[k];
    int o0 = off[k];
    float ax = 0.f, ay = 0.f, az = 0.f, aw = 0.f;
    for (int i = 0; i < cnt; ++i) {
        int r = rowlist[o0 + i];
        float4 zv = (tid < 128) ? ((const float4*)(zr + (size_t)r * 512))[tid]
                                : ((const float4*)(zi + (size_t)r * 512))[tid - 128];
        ax += zv.x; ay += zv.y; az += zv.z; aw += zv.w;
    }
    float4 ew = ((const float4*)(emaw + (size_t)k * 1024))[tid];
    float4 nem;
    nem.x = DECAYF * ew.x + OMD * ax;
    nem.y = DECAYF * ew.y + OMD * ay;
    nem.z = DECAYF * ew.z + OMD * az;
    nem.w = DECAYF * ew.w + OMD * aw;
    ((float4*)(out + OUT_NEMA + (size_t)k * 1024))[tid] = nem;
    float ncs = DECAYF * emacs[k] + OMD * (float)cnt;
    float cs = ncs + 1e-5f;
    if (cs < 1.f) cs += 1.f;
    float inv = 1.f / cs;
    float4 w;
    w.x = fminf(fmaxf(nem.x * inv, -5.f), 5.f);
    w.y = fminf(fmaxf(nem.y * inv, -5.f), 5.f);
    w.z = fminf(fmaxf(nem.z * inv, -5.f), 5.f);
    w.w = fminf(fmaxf(nem.w * inv, -5.f), 5.f);
    ((float4*)(out + OUT_NEWW + (size_t)k * 1024))[tid] = w;
    if (tid == 0) {
        out[OUT_NCS + k] = ncs;
        float p = (float)cnt / 32768.f;
        atomicAdd(entacc, -p * logf(p + 1e-10f));
    }
}

__global__ void ent_fin(const float* __restrict__ entacc, float* __restrict__ out) {
    if (threadIdx.x == 0) out[OUT_ENT] = entacc[0] / logf(8192.f);
}

// ============ 7) z_q gather + loss ============
__global__ __launch_bounds__(256) void zq_loss(
    const float* __restrict__ zr, const float* __restrict__ zi,
    const float* __restrict__ emb, const int* __restrict__ fidx, float* __restrict__ out)
{
    int wave = threadIdx.x >> 6, lane = threadIdx.x & 63;
    int r = blockIdx.x * 4 + wave;
    int idx = fidx[r];
    const float4* ep = (const float4*)(emb + (size_t)idx * 1024);
    float acc = 0.f;
    #pragma unroll
    for (int p = 0; p < 4; ++p) {
        int d4 = p * 64 + lane;
        const float4* zp = (d4 < 128) ? (const float4*)(zr + (size_t)r * 512)
                                      : ((const float4*)(zi + (size_t)r * 512) - 128);
        float4 zv = zp[d4];
        float4 ev = ep[d4];
        float dx = ev.x - zv.x; acc += dx * dx;
        float dy = ev.y - zv.y; acc += dy * dy;
        float dz = ev.z - zv.z; acc += dz * dz;
        float dw = ev.w - zv.w; acc += dw * dw;
        float4* op = (d4 < 128) ? (float4*)(out + OUT_ZQR + (size_t)r * 512)
                                : ((float4*)(out + OUT_ZQI + (size_t)r * 512) - 128);
        op[d4] = ev;
    }
    acc = wredf(acc);
    if (lane == 0) out[OUT_LOSS + r] = 0.25f * acc * (1.f / 1024.f);
}

// ============ launcher ============
extern "C" void kernel_launch(void* const* d_in, const int* in_sizes, int n_in,
                              void* d_out, int out_size, void* d_ws, size_t ws_size,
                              hipStream_t stream)
{
    const float* zr    = (const float*)d_in[0];
    const float* zi    = (const float*)d_in[1];
    const float* emb   = (const float*)d_in[2];
    const float* emacs = (const float*)d_in[3];
    const float* emaw  = (const float*)d_in[4];
    float* out = (float*)d_out;
    char* ws = (char*)d_ws;

    char*  emb8t   = (char*)(ws + WS_EMB8T);
    float* ysq     = (float*)(ws + WS_YSQ);
    int*   nint    = (int*)(ws + WS_NINT);
    float* entacc  = (float*)(ws + WS_ENT);
    int*   ccount  = (int*)(ws + WS_CCOUNT);
    int*   cand    = (int*)(ws + WS_CAND);
    int*   fidx    = (int*)(ws + WS_FIDX);
    int*   off     = (int*)(ws + WS_OFF);
    int*   cur     = (int*)(ws + WS_CUR);
    int*   rowlist = (int*)(ws + WS_ROWLIST);
    long long* pairs = (long long*)out;   // scratch inside z_q_r region

    hipMemsetAsync(ws + WS_NINT, 0, 32768 + 16, stream);   // nint + entacc

    prep_emb   <<<2048, 256, 0, stream>>>(emb, emb8t, ysq);
    argmin_gemm<<<512,  256, 0, stream>>>(zr, zi, emb8t, ysq, pairs);
    merge_rows <<<8192, 256, 0, stream>>>(pairs, cand, ccount);
    cleanup    <<<8192, 256, 0, stream>>>(zr, zi, emb, cand, ccount, fidx, nint, out);
    scan_codes <<<1,    256, 0, stream>>>(nint, off, cur);
    fill_rows  <<<128,  256, 0, stream>>>(fidx, off, cur, rowlist);
    ema_update <<<8192, 256, 0, stream>>>(zr, zi, emaw, emacs, nint, off, rowlist, out, entacc);
    ent_fin    <<<1,    64,  0, stream>>>(entacc, out);
    zq_loss    <<<8192, 256, 0, stream>>>(zr, zi, emb, fidx, out);
}

// Round 7
// 550.865 us; speedup vs baseline: 3.2609x; 1.0672x over previous
//
#include <hip/hip_runtime.h>
#include <hip/hip_bf16.h>

// ---------------- problem constants ----------------
#define NROWS 32768
#define DIM   512
#define D2    1024
#define KCODE 8192
#define DECAYF 0.99f
#define OMD    0.01f
#define CANDCAP 16
#define ZMAX 6.0f
#define IRANGE 0.04419417382415922f   // 1/sqrt(512)
// sfac = 2*(ZMAX/127)*(IRANGE/127); int-score margin 0.30/sfac ~= 9123
#define MARGIN_I 9200

typedef __attribute__((ext_vector_type(4))) float f32x4;
typedef __attribute__((ext_vector_type(4))) int   v4i;
typedef __attribute__((ext_vector_type(16))) int  i32x16;

// ---------------- workspace layout (bytes) ----------------
// emb8t: transposed codebook, per 32-code tile: [64 slots][32 codes][16B] = 32KB
#define WS_EMB8T   0u            // 256 tiles * 32768 = 8,388,608 B
#define WS_YSQ     8388608u      // K int (pre-scaled) = 32,768 B
#define WS_NINT    8421376u      // K int      =     32,768 B
#define WS_ENT     8454144u      // 16 B
#define WS_CCOUNT  8454160u      // N int      =    131,072 B
#define WS_CAND    8585232u      // N*16 int   =  2,097,152 B
#define WS_FIDX    10682384u     // N int      =    131,072 B
#define WS_OFF     10813456u     // K int      =     32,768 B
#define WS_CUR     10846224u     // K int      =     32,768 B
#define WS_ROWLIST 10878992u     // N int      =    131,072 B

// ---------------- output layout (f32 elements, return order) ----------------
#define OUT_ZQR  0
#define OUT_ZQI  16777216
#define OUT_LOSS 33554432
#define OUT_IDX  33587200
#define OUT_ENT  33619968
#define OUT_NEWW 33619969
#define OUT_NCS  42008577
#define OUT_NEMA 42016769
// pairs scratch: 32768 rows x 128 slots x 8B = 33.5MB, lives in OUT_ZQR region;
// consumed by merge_rows, then cleanup overwrites the region with z_q_r.

__device__ __forceinline__ float wredf(float v) {
    #pragma unroll
    for (int o = 32; o > 0; o >>= 1) v += __shfl_down(v, o, 64);
    return v;
}

__device__ __forceinline__ double wredd(double v) {
    #pragma unroll
    for (int o = 32; o > 0; o >>= 1) v += __shfl_down(v, o, 64);
    return __shfl(v, 0, 64);
}

// ULP of float32 at magnitude v (v normal, positive)
__device__ __forceinline__ double ulp32_of(double v) {
    return scalbn(1.0, ilogb(v) - 23);
}

// async global->LDS, 16B per lane; LDS dest = wave-uniform base + lane*16
__device__ __forceinline__ void gload_lds16(const void* g, void* l) {
    __builtin_amdgcn_global_load_lds(
        (const __attribute__((address_space(1))) unsigned int*)(g),
        (__attribute__((address_space(3))) unsigned int*)(l), 16, 0, 0);
}

// quantize 4 floats -> 4 packed i8 (byte0 = x)
__device__ __forceinline__ int q4(float4 v, float s) {
    int a = (int)rintf(fminf(fmaxf(v.x * s, -127.f), 127.f));
    int b = (int)rintf(fminf(fmaxf(v.y * s, -127.f), 127.f));
    int c = (int)rintf(fminf(fmaxf(v.z * s, -127.f), 127.f));
    int d = (int)rintf(fminf(fmaxf(v.w * s, -127.f), 127.f));
    return (a & 255) | ((b & 255) << 8) | ((c & 255) << 16) | ((d & 255) << 24);
}

// ============ 1) y_sq (int grid) + emb -> i8 transposed tile layout ============
__global__ __launch_bounds__(256) void prep_emb(const float* __restrict__ emb,
                                                char* __restrict__ emb8t,
                                                int* __restrict__ ysq) {
    int wave = threadIdx.x >> 6, lane = threadIdx.x & 63;
    int k = blockIdx.x * 4 + wave;
    const float4* src = (const float4*)(emb + (size_t)k * D2);
    const float es = 127.0f / IRANGE;
    const float sfac_inv = 1.0f / (2.0f * (ZMAX / 127.0f) * (IRANGE / 127.0f));
    float s = 0.f;
    float4 v0 = src[lane * 4 + 0];
    float4 v1 = src[lane * 4 + 1];
    float4 v2 = src[lane * 4 + 2];
    float4 v3 = src[lane * 4 + 3];
    s += v0.x*v0.x + v0.y*v0.y + v0.z*v0.z + v0.w*v0.w;
    s += v1.x*v1.x + v1.y*v1.y + v1.z*v1.z + v1.w*v1.w;
    s += v2.x*v2.x + v2.y*v2.y + v2.z*v2.z + v2.w*v2.w;
    s += v3.x*v3.x + v3.y*v3.y + v3.z*v3.z + v3.w*v3.w;
    v4i pk; pk[0] = q4(v0, es); pk[1] = q4(v1, es); pk[2] = q4(v2, es); pk[3] = q4(v3, es);
    v4i* dst = (v4i*)(emb8t + (size_t)(k >> 5) * 32768 + (size_t)lane * 512 + (k & 31) * 16);
    *dst = pk;
    s = wredf(s);
    if (lane == 0) ysq[k] = (int)rintf(s * sfac_inv);
}

// ============ 2) i8 MFMA approx-score: 8 waves, 256 rows, 64-code chunks ============
// Grid 256 = 128 row-blocks x 2 code-slices, 1 block/CU, 2 waves/SIMD.
// Chunk = 64 codes (two 32-code tiles) staged as one 64KB linear copy;
// double-buffered 2x64KB LDS; ONE barrier per 64 codes. Conflict-free reads.
// Int-domain top-2 per lane per row (score = ysq_i - dot_i).
__global__ __launch_bounds__(512, 2) void argmin_gemm(
    const float* __restrict__ zr, const float* __restrict__ zi,
    const char* __restrict__ emb8t, const int* __restrict__ ysq,
    long long* __restrict__ pairs)
{
    __shared__ char bufs[2][65536];
    const int tid  = threadIdx.x;
    const int wave = tid >> 6, lane = tid & 63;
    const int colc = lane & 31;      // A row / B col index
    const int hh   = lane >> 5;      // k-subgroup
    const int rowblk = blockIdx.x >> 1;
    const int slice  = blockIdx.x & 1;

    // ---- A fragments: 32 rows/wave, full K=1024, i8, 128 VGPR ----
    const int arow = rowblk * 256 + wave * 32 + colc;
    const float zs = 127.0f / ZMAX;
    const float* zrp = zr + (size_t)arow * 512 + hh * 16;
    const float* zip = zi + (size_t)arow * 512 + hh * 16;
    v4i afrag[32];
    #pragma unroll
    for (int ft = 0; ft < 16; ++ft) {
        const float4* p = (const float4*)(zrp + ft * 32);
        v4i a; a[0] = q4(p[0], zs); a[1] = q4(p[1], zs); a[2] = q4(p[2], zs); a[3] = q4(p[3], zs);
        afrag[ft] = a;
    }
    #pragma unroll
    for (int ft = 0; ft < 16; ++ft) {
        const float4* p = (const float4*)(zip + ft * 32);
        v4i a; a[0] = q4(p[0], zs); a[1] = q4(p[1], zs); a[2] = q4(p[2], zs); a[3] = q4(p[3], zs);
        afrag[16 + ft] = a;
    }

    // per-lane per-row top-2 int scores (sorted tv0<=tv1), tile ids packed 2x8b
    int tv0[16], tv1[16], cpk[16];
    #pragma unroll
    for (int g = 0; g < 16; ++g) { tv0[g] = 0x7FFFFFFF; tv1[g] = 0x7FFFFFFF; cpk[g] = 0; }

    const char* gslice = emb8t + (size_t)slice * 128 * 32768;
    const int* yslice = ysq + slice * 4096;

    // stage 64-code chunk: 64KB linear copy, 8 x gload16 per wave (8KB/wave)
#define STAGE(dstbuf, c_) do {                                                   \
        const char* gb = gslice + (size_t)(c_) * 65536 + wave * 8192             \
                       + (size_t)lane * 16;                                      \
        char* lb = (dstbuf) + wave * 8192;                                       \
        _Pragma("unroll")                                                        \
        for (int q = 0; q < 8; ++q)                                              \
            gload_lds16(gb + q * 1024, lb + q * 1024);                           \
    } while (0)

    const int boff = colc * 16 + hh * 512;

    STAGE(bufs[0], 0);
    __syncthreads();

    for (int c = 0; c < 64; ++c) {
        const int cur = c & 1;
        if (c + 1 < 64) STAGE(bufs[cur ^ 1], c + 1);

        const char* bb = &bufs[cur][0] + boff;
        i32x16 accA, accB;
        #pragma unroll
        for (int g = 0; g < 16; ++g) { accA[g] = 0; accB[g] = 0; }
        #pragma unroll
        for (int m = 0; m < 32; ++m) {
            v4i bA = *(const v4i*)(bb + m * 1024);
            v4i bB = *(const v4i*)(bb + m * 1024 + 32768);
            accA = __builtin_amdgcn_mfma_i32_32x32x32_i8(afrag[m], bA, accA, 0, 0, 0);
            accB = __builtin_amdgcn_mfma_i32_32x32x32_i8(afrag[m], bB, accB, 0, 0, 0);
        }

        int ysA = yslice[c * 64 + colc];
        int ysB = yslice[c * 64 + 32 + colc];
        const int idA = c * 2, idB = c * 2 + 1;
        #pragma unroll
        for (int g = 0; g < 16; ++g) {
            int sc = ysA - accA[g];
            if (sc < tv1[g]) {
                bool b0 = sc < tv0[g];
                int cp = cpk[g];
                cpk[g] = b0 ? (((cp & 0xFF) << 8) | idA) : ((cp & 0xFF) | (idA << 8));
                int ov0 = tv0[g];
                tv1[g] = b0 ? ov0 : sc;
                tv0[g] = b0 ? sc : ov0;
            }
            sc = ysB - accB[g];
            if (sc < tv1[g]) {
                bool b0 = sc < tv0[g];
                int cp = cpk[g];
                cpk[g] = b0 ? (((cp & 0xFF) << 8) | idB) : ((cp & 0xFF) | (idB << 8));
                int ov0 = tv0[g];
                tv1[g] = b0 ? ov0 : sc;
                tv0[g] = b0 ? sc : ov0;
            }
        }
        __syncthreads();
    }
#undef STAGE

    // ---- write per-lane top-2 to pair buffer: pairs[row][slice*64 + col*2 + t] ----
    #pragma unroll
    for (int g = 0; g < 16; ++g) {
        int rloc = (g & 3) + 8 * (g >> 2) + 4 * hh;       // C/D row mapping (m74/m101)
        int rowg = rowblk * 256 + wave * 32 + rloc;
        size_t base = (size_t)rowg * 128 + slice * 64 + colc * 2;
        int cp = cpk[g];
        int code0 = slice * 4096 + (cp & 0xFF) * 32 + colc;
        int code1 = slice * 4096 + ((cp >> 8) & 0xFF) * 32 + colc;
        pairs[base + 0] = ((long long)(unsigned)code0 << 32) | (unsigned)tv0[g];
        pairs[base + 1] = ((long long)(unsigned)code1 << 32) | (unsigned)tv1[g];
    }
}

// ============ 2b) per-row merge of 128 pair slots -> candidate list (int) ============
__global__ __launch_bounds__(256) void merge_rows(const long long* __restrict__ pairs,
                                                  int* __restrict__ cand,
                                                  int* __restrict__ ccount)
{
    int wave = threadIdx.x >> 6, lane = threadIdx.x & 63;
    int row = blockIdx.x * 4 + wave;
    const long long* pr = pairs + (size_t)row * 128;
    long long p0 = pr[lane];
    long long p1 = pr[64 + lane];
    int v0v = (int)(unsigned)p0;
    int i0  = (int)(p0 >> 32);
    int v1v = (int)(unsigned)p1;
    int i1  = (int)(p1 >> 32);
    int m = min(v0v, v1v);
    #pragma unroll
    for (int o = 32; o > 0; o >>= 1) m = min(m, __shfl_xor(m, o, 64));
    int lim = m + MARGIN_I;
    unsigned long long m0 = __ballot(v0v < lim);
    unsigned long long m1 = __ballot(v1v < lim);
    int t0 = __popcll(m0);
    int cnt = t0 + __popcll(m1);
    if (cnt > CANDCAP) cnt = CANDCAP;
    unsigned long long below = (lane == 63) ? 0xFFFFFFFFFFFFFFFFull >> 1
                                            : ((1ull << lane) - 1);
    if (v0v < lim) {
        int pos = __popcll(m0 & below);
        if (pos < CANDCAP) cand[(size_t)row * CANDCAP + pos] = i0;
    }
    if (v1v < lim) {
        int pos = t0 + __popcll(m1 & below);
        if (pos < CANDCAP) cand[(size_t)row * CANDCAP + pos] = i1;
    }
    if (lane == 0) ccount[row] = cnt;
}

// ============ 3) fused: numpy-f32-pipeline rescore + idx + z_q + loss + hist ============
// np: d = fl32( fl32(x_sq + y_sq) - 2*fl32(dot) ), argmin lowest-index-first.
// x_sq lies ON the f32 grid of its own binade -> cancels; compare
// D_k = G_uS(y_k) - G_ud(2 t_k), grid G_u(v) = rint(v/u)*u, ties -> lower index.
__global__ __launch_bounds__(256) void cleanup(
    const float* __restrict__ zr, const float* __restrict__ zi,
    const float* __restrict__ emb, const int* __restrict__ cand,
    const int* __restrict__ ccount, int* __restrict__ fidx,
    int* __restrict__ nint, float* __restrict__ out)
{
    int wave = threadIdx.x >> 6, lane = threadIdx.x & 63;
    int r = blockIdx.x * 4 + wave;
    int cnt = ccount[r];
    int best = cand[r * CANDCAP];

    // z row in registers (always needed: rescore + z_q/loss epilogue)
    float zreg[16];
    #pragma unroll
    for (int p = 0; p < 4; ++p) {
        int d4 = p * 64 + lane;
        const float4* zp = (d4 < 128) ? (const float4*)(zr + (size_t)r * 512)
                                      : ((const float4*)(zi + (size_t)r * 512) - 128);
        float4 zv = zp[d4];
        zreg[p * 4 + 0] = zv.x; zreg[p * 4 + 1] = zv.y;
        zreg[p * 4 + 2] = zv.z; zreg[p * 4 + 3] = zv.w;
    }

    if (cnt > 1) {
        double xs = 0.0;
        #pragma unroll
        for (int j = 0; j < 16; ++j) xs += (double)zreg[j] * (double)zreg[j];
        xs = wredd(xs);
        double uS = ulp32_of(xs);

        double bD = 1e300; int bi = 1 << 30;
        for (int i = 0; i < cnt; ++i) {
            int cdx = cand[r * CANDCAP + i];
            const float4* ep = (const float4*)(emb + (size_t)cdx * 1024);
            double ys = 0.0, tt = 0.0;
            #pragma unroll
            for (int p = 0; p < 4; ++p) {
                float4 ev = ep[p * 64 + lane];
                float p0 = ev.x * ev.x, p1 = ev.y * ev.y, p2 = ev.z * ev.z, p3 = ev.w * ev.w;
                ys += (double)p0 + (double)p1 + (double)p2 + (double)p3;
                tt += (double)zreg[p * 4 + 0] * (double)ev.x
                    + (double)zreg[p * 4 + 1] * (double)ev.y
                    + (double)zreg[p * 4 + 2] * (double)ev.z
                    + (double)zreg[p * 4 + 3] * (double)ev.w;
            }
            ys = wredd(ys);
            tt = wredd(tt);
            float y32 = (float)ys;
            float t32 = (float)tt;
            double dex = xs + ys - 2.0 * tt;
            double ud = ulp32_of(dex);
            double D = rint((double)y32 / uS) * uS - rint(2.0 * (double)t32 / ud) * ud;
            if (D < bD || (D == bD && cdx < bi)) { bD = D; bi = cdx; }
        }
        best = bi;
    }

    // epilogue: z_q gather + loss from registers
    const float4* ep = (const float4*)(emb + (size_t)best * 1024);
    float acc = 0.f;
    #pragma unroll
    for (int p = 0; p < 4; ++p) {
        int d4 = p * 64 + lane;
        float4 ev = ep[d4];
        float dx = ev.x - zreg[p * 4 + 0]; acc += dx * dx;
        float dy = ev.y - zreg[p * 4 + 1]; acc += dy * dy;
        float dz = ev.z - zreg[p * 4 + 2]; acc += dz * dz;
        float dw = ev.w - zreg[p * 4 + 3]; acc += dw * dw;
        float4* op = (d4 < 128) ? (float4*)(out + OUT_ZQR + (size_t)r * 512)
                                : ((float4*)(out + OUT_ZQI + (size_t)r * 512) - 128);
        op[d4] = ev;
    }
    acc = wredf(acc);
    if (lane == 0) {
        fidx[r] = best;
        out[OUT_IDX + r] = (float)best;
        out[OUT_LOSS + r] = 0.25f * acc * (1.f / 1024.f);
        atomicAdd(nint + best, 1);
    }
}

// ============ 4) exclusive prefix sum over K=8192 bucket counts ============
__global__ __launch_bounds__(256) void scan_codes(const int* __restrict__ nint,
                                                  int* __restrict__ off,
                                                  int* __restrict__ cur) {
    __shared__ int part[256];
    int tid = threadIdx.x;
    int base = tid * 32;
    int loc[32];
    int s = 0;
    #pragma unroll
    for (int j = 0; j < 32; ++j) { loc[j] = s; s += nint[base + j]; }
    part[tid] = s;
    __syncthreads();
    for (int o = 1; o < 256; o <<= 1) {
        int t = (tid >= o) ? part[tid - o] : 0;
        __syncthreads();
        part[tid] += t;
        __syncthreads();
    }
    int excl = part[tid] - s;
    #pragma unroll
    for (int j = 0; j < 32; ++j) {
        off[base + j] = excl + loc[j];
        cur[base + j] = 0;
    }
}

// ============ 5) bucket fill: rowlist grouped by assigned code ============
__global__ __launch_bounds__(256) void fill_rows(const int* __restrict__ fidx,
                                                 const int* __restrict__ off,
                                                 int* __restrict__ cur,
                                                 int* __restrict__ rowlist) {
    int r = blockIdx.x * 256 + threadIdx.x;
    int idx = fidx[r];
    int pos = atomicAdd(cur + idx, 1);
    rowlist[off[idx] + pos] = r;
}

// ============ 6) fused EMA tail: one block per code ============
__global__ __launch_bounds__(256) void ema_update(
    const float* __restrict__ zr, const float* __restrict__ zi,
    const float* __restrict__ emaw, const float* __restrict__ emacs,
    const int* __restrict__ nint, const int* __restrict__ off,
    const int* __restrict__ rowlist, float* __restrict__ out,
    float* __restrict__ entacc)
{
    int k = blockIdx.x;
    int tid = threadIdx.x;
    int cnt = nint[k];
    int o0 = off[k];
    float ax = 0.f, ay = 0.f, az = 0.f, aw = 0.f;
    for (int i = 0; i < cnt; ++i) {
        int r = rowlist[o0 + i];
        float4 zv = (tid < 128) ? ((const float4*)(zr + (size_t)r * 512))[tid]
                                : ((const float4*)(zi + (size_t)r * 512))[tid - 128];
        ax += zv.x; ay += zv.y; az += zv.z; aw += zv.w;
    }
    float4 ew = ((const float4*)(emaw + (size_t)k * 1024))[tid];
    float4 nem;
    nem.x = DECAYF * ew.x + OMD * ax;
    nem.y = DECAYF * ew.y + OMD * ay;
    nem.z = DECAYF * ew.z + OMD * az;
    nem.w = DECAYF * ew.w + OMD * aw;
    ((float4*)(out + OUT_NEMA + (size_t)k * 1024))[tid] = nem;
    float ncs = DECAYF * emacs[k] + OMD * (float)cnt;
    float cs = ncs + 1e-5f;
    if (cs < 1.f) cs += 1.f;
    float inv = 1.f / cs;
    float4 w;
    w.x = fminf(fmaxf(nem.x * inv, -5.f), 5.f);
    w.y = fminf(fmaxf(nem.y * inv, -5.f), 5.f);
    w.z = fminf(fmaxf(nem.z * inv, -5.f), 5.f);
    w.w = fminf(fmaxf(nem.w * inv, -5.f), 5.f);
    ((float4*)(out + OUT_NEWW + (size_t)k * 1024))[tid] = w;
    if (tid == 0) {
        out[OUT_NCS + k] = ncs;
        float p = (float)cnt / 32768.f;
        atomicAdd(entacc, -p * logf(p + 1e-10f));
    }
}

__global__ void ent_fin(const float* __restrict__ entacc, float* __restrict__ out) {
    if (threadIdx.x == 0) out[OUT_ENT] = entacc[0] / logf(8192.f);
}

// ============ launcher ============
extern "C" void kernel_launch(void* const* d_in, const int* in_sizes, int n_in,
                              void* d_out, int out_size, void* d_ws, size_t ws_size,
                              hipStream_t stream)
{
    const float* zr    = (const float*)d_in[0];
    const float* zi    = (const float*)d_in[1];
    const float* emb   = (const float*)d_in[2];
    const float* emacs = (const float*)d_in[3];
    const float* emaw  = (const float*)d_in[4];
    float* out = (float*)d_out;
    char* ws = (char*)d_ws;

    char*  emb8t   = (char*)(ws + WS_EMB8T);
    int*   ysq     = (int*)(ws + WS_YSQ);
    int*   nint    = (int*)(ws + WS_NINT);
    float* entacc  = (float*)(ws + WS_ENT);
    int*   ccount  = (int*)(ws + WS_CCOUNT);
    int*   cand    = (int*)(ws + WS_CAND);
    int*   fidx    = (int*)(ws + WS_FIDX);
    int*   off     = (int*)(ws + WS_OFF);
    int*   cur     = (int*)(ws + WS_CUR);
    int*   rowlist = (int*)(ws + WS_ROWLIST);
    long long* pairs = (long long*)out;   // scratch inside z_q_r region

    hipMemsetAsync(ws + WS_NINT, 0, 32768 + 16, stream);   // nint + entacc

    prep_emb   <<<2048, 256, 0, stream>>>(emb, emb8t, ysq);
    argmin_gemm<<<256,  512, 0, stream>>>(zr, zi, emb8t, ysq, pairs);
    merge_rows <<<8192, 256, 0, stream>>>(pairs, cand, ccount);
    cleanup    <<<8192, 256, 0, stream>>>(zr, zi, emb, cand, ccount, fidx, nint, out);
    scan_codes <<<1,    256, 0, stream>>>(nint, off, cur);
    fill_rows  <<<128,  256, 0, stream>>>(fidx, off, cur, rowlist);
    ema_update <<<8192, 256, 0, stream>>>(zr, zi, emaw, emacs, nint, off, rowlist, out, entacc);
    ent_fin    <<<1,    64,  0, stream>>>(entacc, out);
}